// Round 12
// baseline (114.842 us; speedup 1.0000x reference)
//
#include <hip/hip_runtime.h>
#include <math.h>

#define G 160
#define GM1 159
#define NS 558
#define CHSTRIDE (160 * 160 * 160)
#define G3 (160 * 160 * 160)

#define DENS_SCALE (10.0f / 255.0f)
#define DENS_BIAS  (-5.0f)
#define COL_SCALE  (7.0f / 255.0f)
#define COL_BIAS   (-3.5f)

#define NCELL 512
#define MAXRAYS 16384

// ---------------- fused prep: block 0 sorts (ray,half) tasks, others pack grid ----------------

__device__ __forceinline__ unsigned int q8(float v, float bias, float invscale) {
    return (unsigned int)lrintf(fminf(fmaxf((v - bias) * invscale, 0.f), 255.f));
}

__global__ __launch_bounds__(1024) void prep_fused(
    const float* __restrict__ dens,
    const float* __restrict__ k0,
    const float* __restrict__ rays_o,
    const float* __restrict__ rays_d,
    unsigned int* __restrict__ packed,
    unsigned int* __restrict__ order, int N)   // order[0..N)=A-tasks sorted, [N..2N)=B-tasks sorted
{
    __shared__ unsigned short skeys[MAXRAYS];   // 32 KB
    __shared__ unsigned int hist[NCELL];
    __shared__ unsigned int tmp[NCELL];
    __shared__ unsigned int offs[NCELL];

    const int tid = threadIdx.x;

    if (blockIdx.x == 0) {
        // two counting-sort passes: entry cell into sub-box h (A: x<0, B: x>=0)
        for (int h = 0; h < 2; ++h) {
            for (int i = tid; i < NCELL; i += 1024) hist[i] = 0;
            __syncthreads();
            const float xlo = h ? 0.f : -1.f;
            const float xhi = h ? 1.f : 0.f;
            for (int r = tid; r < N; r += 1024) {
                const float ox = rays_o[r * 3 + 0], oy = rays_o[r * 3 + 1], oz = rays_o[r * 3 + 2];
                const float dx = rays_d[r * 3 + 0], dy = rays_d[r * 3 + 1], dz = rays_d[r * 3 + 2];
                const float vx = (dx == 0.f) ? 1e-6f : dx;
                const float vy = (dy == 0.f) ? 1e-6f : dy;
                const float vz = (dz == 0.f) ? 1e-6f : dz;
                const float raxh = (xhi - ox) / vx, rbxh = (xlo - ox) / vx;
                const float ray_ = (1.f - oy) / vy, rby = (-1.f - oy) / vy;
                const float raz = (1.f - oz) / vz, rbz = (-1.f - oz) / vz;
                float tminH = fmaxf(fmaxf(fminf(raxh, rbxh), fminf(ray_, rby)), fminf(raz, rbz));
                tminH = fminf(fmaxf(tminH, 0.2f), 6.0f);
                const float px = fminf(fmaxf(fmaf(dx, tminH, ox), -1.f), 1.f);
                const float py = fminf(fmaxf(fmaf(dy, tminH, oy), -1.f), 1.f);
                const float pz = fminf(fmaxf(fmaf(dz, tminH, oz), -1.f), 1.f);
                const int cx = min(7, (int)((px + 1.f) * 4.f));
                const int cy = min(7, (int)((py + 1.f) * 4.f));
                const int cz = min(7, (int)((pz + 1.f) * 4.f));
                const unsigned int key = (unsigned int)((cx << 6) | (cy << 3) | cz);
                skeys[r] = (unsigned short)key;
                atomicAdd(&hist[key], 1u);
            }
            __syncthreads();
            if (tid < NCELL) tmp[tid] = hist[tid];
            __syncthreads();
            for (int off = 1; off < NCELL; off <<= 1) {
                unsigned int v = 0;
                if (tid < NCELL && tid >= off) v = tmp[tid - off];
                __syncthreads();
                if (tid < NCELL) tmp[tid] += v;
                __syncthreads();
            }
            if (tid < NCELL) offs[tid] = tmp[tid] - hist[tid];
            __syncthreads();
            for (int r = tid; r < N; r += 1024) {
                const unsigned int pos = atomicAdd(&offs[skeys[r]], 1u);
                order[h * N + pos] = (unsigned int)r;
            }
            __syncthreads();
        }
    } else {
        // ---- pack 4 voxels/thread: {dens, k0.rgb} -> u8x4 ----
        const int base = ((blockIdx.x - 1) * 1024 + tid) * 4;
        if (base + 3 < G3) {
            const float4 d = *(const float4*)(dens + base);
            const float4 r = *(const float4*)(k0 + base);
            const float4 g = *(const float4*)(k0 + CHSTRIDE + base);
            const float4 b = *(const float4*)(k0 + 2 * CHSTRIDE + base);
            const float dis = 255.f / 10.f, cis = 255.f / 7.f;
            uint4 o;
            o.x = q8(d.x, DENS_BIAS, dis) | (q8(r.x, COL_BIAS, cis) << 8) |
                  (q8(g.x, COL_BIAS, cis) << 16) | (q8(b.x, COL_BIAS, cis) << 24);
            o.y = q8(d.y, DENS_BIAS, dis) | (q8(r.y, COL_BIAS, cis) << 8) |
                  (q8(g.y, COL_BIAS, cis) << 16) | (q8(b.y, COL_BIAS, cis) << 24);
            o.z = q8(d.z, DENS_BIAS, dis) | (q8(r.z, COL_BIAS, cis) << 8) |
                  (q8(g.z, COL_BIAS, cis) << 16) | (q8(b.z, COL_BIAS, cis) << 24);
            o.w = q8(d.w, DENS_BIAS, dis) | (q8(r.w, COL_BIAS, cis) << 8) |
                  (q8(g.w, COL_BIAS, cis) << 16) | (q8(b.w, COL_BIAS, cis) << 24);
            *(uint4*)(packed + base) = o;
        }
    }
}

// ---------------- render: per-(ray,half) task, 2-deep pipelined, branchless ----------------

__device__ __forceinline__ float ub(unsigned int q, int c) {
    return (float)((q >> (c * 8)) & 0xffu);   // v_cvt_f32_ubyte{c}
}

struct SampleData {
    unsigned int q000, q001, q010, q011, q100, q101, q110, q111;
    float w000, w001, w010, w011, w100, w101, w110, w111;
    float amask;
};

__device__ __forceinline__ SampleData fetch_sample(
    const unsigned int* __restrict__ pg,
    float ex, float ey, float ez, float gx, float gy, float gz, int s, int half)
{
    SampleData r;
    const float sF = (float)s;
    const float fx = fmaf(gx, sF, ex);
    const float fy = fmaf(gy, sF, ey);
    const float fz = fmaf(gz, sF, ez);
    const float mn  = fminf(fminf(fx, fy), fz);
    const float mx_ = fmaxf(fmaxf(fx, fy), fz);
    // half-plane partition in index space: A = fx < 79.5, B = fx >= 79.5.
    // Identical fused expression in both tasks -> exact partition of every sample.
    const bool hs = half ? (fx >= 79.5f) : (fx < 79.5f);
    r.amask = (mn >= 0.f && mx_ <= 159.f && hs) ? 1.f : 0.f;
    const float cfx = __builtin_amdgcn_fmed3f(fx, 0.f, 159.f);
    const float cfy = __builtin_amdgcn_fmed3f(fy, 0.f, 159.f);
    const float cfz = __builtin_amdgcn_fmed3f(fz, 0.f, 159.f);
    const int x0 = (int)cfx; const float tx = cfx - (float)x0;
    const int y0 = (int)cfy; const float ty = cfy - (float)y0;
    const int z0 = (int)cfz; const float tz = cfz - (float)z0;
    const int x1 = min(x0 + 1, GM1);
    const int y1 = min(y0 + 1, GM1);
    // z1 unclamped: z0==159 => tz==0 => zero weight; 4B overrun lands in order[] (finite).
    const float mx = 1.f - tx, my = 1.f - ty, mz = 1.f - tz;
    const float w00 = mx * my, w01 = mx * ty, w10 = tx * my, w11 = tx * ty;
    r.w000 = w00 * mz; r.w001 = w00 * tz;
    r.w010 = w01 * mz; r.w011 = w01 * tz;
    r.w100 = w10 * mz; r.w101 = w10 * tz;
    r.w110 = w11 * mz; r.w111 = w11 * tz;
    const int xg0 = x0 * G, xg1 = x1 * G;
    const int i00 = (xg0 + y0) * G + z0;
    const int i01 = (xg0 + y1) * G + z0;
    const int i10 = (xg1 + y0) * G + z0;
    const int i11 = (xg1 + y1) * G + z0;
    r.q000 = pg[i00]; r.q001 = pg[i00 + 1];
    r.q010 = pg[i01]; r.q011 = pg[i01 + 1];
    r.q100 = pg[i10]; r.q101 = pg[i10 + 1];
    r.q110 = pg[i11]; r.q111 = pg[i11 + 1];
    return r;
}

__device__ __forceinline__ void composite(const SampleData& d, int lane,
    float& T, float& ar, float& ag, float& ab)
{
    const float ACT_SHIFT = -4.59511985013459f;
    float acc[4];
    #pragma unroll
    for (int ch = 0; ch < 4; ++ch) {
        acc[ch] = d.w000 * ub(d.q000, ch) + d.w001 * ub(d.q001, ch) +
                  d.w010 * ub(d.q010, ch) + d.w011 * ub(d.q011, ch) +
                  d.w100 * ub(d.q100, ch) + d.w101 * ub(d.q101, ch) +
                  d.w110 * ub(d.q110, ch) + d.w111 * ub(d.q111, ch);
    }
    const float dens = fmaf(acc[0], DENS_SCALE, DENS_BIAS);
    const float vr   = fmaf(acc[1], COL_SCALE,  COL_BIAS);
    const float vg   = fmaf(acc[2], COL_SCALE,  COL_BIAS);
    const float vb   = fmaf(acc[3], COL_SCALE,  COL_BIAS);
    const float e = __expf(dens + ACT_SHIFT);
    const float oma = __builtin_amdgcn_rsqf(1.f + e);   // 1 - alpha_raw
    const float alpha = (1.f - oma) * d.amask;
    const float cr = __builtin_amdgcn_rcpf(1.f + __expf(-vr));
    const float cg = __builtin_amdgcn_rcpf(1.f + __expf(-vg));
    const float cb = __builtin_amdgcn_rcpf(1.f + __expf(-vb));

    const float one_m_a = 1.f - alpha;    // >= 0.63 (u8 density clamp)
    float incl = one_m_a;
    #pragma unroll
    for (int off = 1; off < 64; off <<= 1) {
        const float v = __shfl_up(incl, off, 64);
        if (lane >= off) incl *= v;
    }
    const float excl = incl * __builtin_amdgcn_rcpf(one_m_a);
    const float w = alpha * T * excl;
    ar = fmaf(w, cr, ar);
    ag = fmaf(w, cg, ag);
    ab = fmaf(w, cb, ab);
    T *= __shfl(incl, 63, 64);
}

__global__ __launch_bounds__(256) void dvgo_render_split(
    const float* __restrict__ rays_o,
    const float* __restrict__ rays_d,
    const unsigned int* __restrict__ pg,
    const unsigned int* __restrict__ order,
    float4* __restrict__ partials, int N)      // partials[half*N + ray] = (r,g,b,T)
{
    // XCDs 0-3 -> half A (x<0), XCDs 4-7 -> half B. 64-block chunk interleave
    // within each half for ray-length balance; grid is exactly 2N/4 blocks.
    const unsigned int bid  = blockIdx.x;
    const unsigned int xcd  = bid & 7u;
    const int half          = (int)(xcd >> 2);
    const unsigned int xcdh = xcd & 3u;
    const unsigned int j    = bid >> 3;          // 0..(N/16-1)  (1024 for N=16384)
    const unsigned int cseq = j >> 6;
    const unsigned int pos  = j & 63u;
    const unsigned int bidp = (cseq * 4u + xcdh) * 64u + pos;   // within-half block
    const int slot = (int)(bidp * 4u + (threadIdx.x >> 6));
    const int lane = (int)(threadIdx.x & 63u);
    const int ray  = (int)order[half * N + slot];

    const float ox = rays_o[ray * 3 + 0], oy = rays_o[ray * 3 + 1], oz = rays_o[ray * 3 + 2];
    const float dx = rays_d[ray * 3 + 0], dy = rays_d[ray * 3 + 1], dz = rays_d[ray * 3 + 2];
    const float inv_norm = __builtin_amdgcn_rsqf(dx * dx + dy * dy + dz * dz);

    const float vx = (dx == 0.f) ? 1e-6f : dx;
    const float vy = (dy == 0.f) ? 1e-6f : dy;
    const float vz = (dz == 0.f) ? 1e-6f : dz;
    const float rax = (1.f - ox) / vx, rbx = (-1.f - ox) / vx;
    const float ray_ = (1.f - oy) / vy, rby = (-1.f - oy) / vy;
    const float raz = (1.f - oz) / vz, rbz = (-1.f - oz) / vz;
    const float tyzmin = fmaxf(fminf(ray_, rby), fminf(raz, rbz));
    const float tyzmax = fminf(fmaxf(ray_, rby), fmaxf(raz, rbz));
    float tmin = fmaxf(tyzmin, fminf(rax, rbx));
    float tmax = fminf(tyzmax, fmaxf(rax, rbx));
    tmin = fminf(fmaxf(tmin, 0.2f), 6.0f);
    tmax = fminf(fmaxf(tmax, 0.2f), 6.0f);

    const float dt = 0.00625f * inv_norm;

    int n_samp = 0;
    if (!(tmax < tmin)) n_samp = min(NS, (int)((tmax - tmin) / dt) + 2);

    // sub-box slab (this half) -> sample index range [s0, s1)
    const float xlo = half ? 0.f : -1.f;
    const float xhi = half ? 1.f : 0.f;
    const float raxh = (xhi - ox) / vx, rbxh = (xlo - ox) / vx;
    float tminH = fmaxf(tyzmin, fminf(raxh, rbxh));
    float tmaxH = fminf(tyzmax, fmaxf(raxh, rbxh));
    tminH = fminf(fmaxf(tminH, 0.2f), 6.0f);
    tmaxH = fminf(fmaxf(tmaxH, 0.2f), 6.0f);

    int s0 = 0, s1 = 0;
    if (n_samp > 0 && !(tmaxH < tminH)) {
        s0 = max(0, (int)((tminH - tmin) / dt) - 2);
        s1 = min(n_samp, (int)((tmaxH - tmin) / dt) + 3);
    }
    const int n_chunks = (s1 > s0) ? ((s1 - s0 + 63) >> 6) : 0;

    // ray fused into index space: f = fmaf(g, s, e), s absolute
    const float ex = (fmaf(dx, tmin, ox) + 1.f) * 79.5f;
    const float ey = (fmaf(dy, tmin, oy) + 1.f) * 79.5f;
    const float ez = (fmaf(dz, tmin, oz) + 1.f) * 79.5f;
    const float gx = dx * dt * 79.5f;
    const float gy = dy * dt * 79.5f;
    const float gz = dz * dt * 79.5f;

    float T = 1.f;
    float ar = 0.f, ag = 0.f, ab = 0.f;

    if (n_chunks > 0) {
        SampleData sd0 = fetch_sample(pg, ex, ey, ez, gx, gy, gz, s0 + lane, half);
        SampleData sd1;
        if (n_chunks > 1) sd1 = fetch_sample(pg, ex, ey, ez, gx, gy, gz, s0 + 64 + lane, half);
        for (int c = 0; c < n_chunks; ++c) {
            SampleData sd2;
            if (c + 2 < n_chunks)
                sd2 = fetch_sample(pg, ex, ey, ez, gx, gy, gz, s0 + ((c + 2) << 6) + lane, half);

            composite(sd0, lane, T, ar, ag, ab);

            sd0 = sd1;
            sd1 = sd2;
        }
    }

    #pragma unroll
    for (int off = 32; off > 0; off >>= 1) {
        ar += __shfl_down(ar, off, 64);
        ag += __shfl_down(ag, off, 64);
        ab += __shfl_down(ab, off, 64);
    }
    if (lane == 0) {
        partials[half * N + ray] = make_float4(ar, ag, ab, T);
    }
}

// ---------------- combine: rgb = rgb_first + T_first*rgb_second (+ T*BG) ----------------

__global__ __launch_bounds__(256) void combine_halves(
    const float* __restrict__ rays_o,
    const float* __restrict__ rays_d,
    const float4* __restrict__ partials,
    float* __restrict__ out, int N)
{
    const int r = blockIdx.x * 256 + threadIdx.x;
    if (r >= N) return;
    const float ox = rays_o[r * 3 + 0], oy = rays_o[r * 3 + 1], oz = rays_o[r * 3 + 2];
    const float dx = rays_d[r * 3 + 0], dy = rays_d[r * 3 + 1], dz = rays_d[r * 3 + 2];
    const float vx = (dx == 0.f) ? 1e-6f : dx;
    const float vy = (dy == 0.f) ? 1e-6f : dy;
    const float vz = (dz == 0.f) ? 1e-6f : dz;
    const float rax = (1.f - ox) / vx, rbx = (-1.f - ox) / vx;
    const float ray_ = (1.f - oy) / vy, rby = (-1.f - oy) / vy;
    const float raz = (1.f - oz) / vz, rbz = (-1.f - oz) / vz;
    const float tyzmin = fmaxf(fminf(ray_, rby), fminf(raz, rbz));
    float tmin = fmaxf(tyzmin, fminf(rax, rbx));
    tmin = fminf(fmaxf(tmin, 0.2f), 6.0f);
    // identical expression to render's ex -> consistent first-half decision
    const float ex = (fmaf(dx, tmin, ox) + 1.f) * 79.5f;

    const float4 a = partials[r];         // half A (x<0)
    const float4 b = partials[N + r];     // half B (x>=0)
    float4 f, s;
    if (ex < 79.5f) { f = a; s = b; } else { f = b; s = a; }
    const float Ttot = f.w * s.w;
    out[r * 3 + 0] = f.x + f.w * s.x + Ttot;
    out[r * 3 + 1] = f.y + f.w * s.y + Ttot;
    out[r * 3 + 2] = f.z + f.w * s.z + Ttot;
}

// ---------------- fallback: f32 4-array render (ws too small / N mismatch) ----------------

__global__ __launch_bounds__(256) void dvgo_render_f32(
    const float* __restrict__ rays_o,
    const float* __restrict__ rays_d,
    const float* __restrict__ dens_g,
    const float* __restrict__ k0_g,
    float* __restrict__ out, int N)
{
    const int wave = (int)((blockIdx.x * 256u + threadIdx.x) >> 6);
    const int lane = (int)(threadIdx.x & 63u);
    if (wave >= N) return;

    const float ox = rays_o[wave * 3 + 0], oy = rays_o[wave * 3 + 1], oz = rays_o[wave * 3 + 2];
    const float dx = rays_d[wave * 3 + 0], dy = rays_d[wave * 3 + 1], dz = rays_d[wave * 3 + 2];
    const float inv_norm = rsqrtf(dx * dx + dy * dy + dz * dz);

    const float vx = (dx == 0.f) ? 1e-6f : dx;
    const float vy = (dy == 0.f) ? 1e-6f : dy;
    const float vz = (dz == 0.f) ? 1e-6f : dz;
    const float rax = (1.f - ox) / vx, rbx = (-1.f - ox) / vx;
    const float ray_ = (1.f - oy) / vy, rby = (-1.f - oy) / vy;
    const float raz = (1.f - oz) / vz, rbz = (-1.f - oz) / vz;
    float tmin = fmaxf(fmaxf(fminf(rax, rbx), fminf(ray_, rby)), fminf(raz, rbz));
    float tmax = fminf(fminf(fmaxf(rax, rbx), fmaxf(ray_, rby)), fmaxf(raz, rbz));
    tmin = fminf(fmaxf(tmin, 0.2f), 6.0f);
    tmax = fminf(fmaxf(tmax, 0.2f), 6.0f);
    const bool ray_oob = (tmax < tmin);

    const float dt = 0.00625f * inv_norm;
    const float ACT_SHIFT = -4.59511985013459f;

    float T = 1.f;
    float ar = 0.f, ag = 0.f, ab = 0.f;

    for (int s0 = 0; s0 < NS; s0 += 64) {
        const int s = s0 + lane;
        float alpha = 0.f, cr = 0.f, cg = 0.f, cb = 0.f;
        bool valid = false;
        if (!ray_oob && s < NS) {
            const float t = tmin + dt * (float)s;
            const float px = fmaf(dx, t, ox);
            const float py = fmaf(dy, t, oy);
            const float pz = fmaf(dz, t, oz);
            if (px >= -1.f && px <= 1.f && py >= -1.f && py <= 1.f &&
                pz >= -1.f && pz <= 1.f) {
                valid = true;
                const float fx = (px + 1.f) * 79.5f;
                const float fy = (py + 1.f) * 79.5f;
                const float fz = (pz + 1.f) * 79.5f;
                int x0 = (int)fx; const float tx = fx - (float)x0;
                int y0 = (int)fy; const float ty = fy - (float)y0;
                int z0 = (int)fz; const float tz = fz - (float)z0;
                x0 = min(x0, GM1); y0 = min(y0, GM1); z0 = min(z0, GM1);
                const int x1 = min(x0 + 1, GM1);
                const int y1 = min(y0 + 1, GM1);
                const int z1 = min(z0 + 1, GM1);

                const float mx = 1.f - tx, my = 1.f - ty, mz = 1.f - tz;
                const float w00 = mx * my, w01 = mx * ty, w10 = tx * my, w11 = tx * ty;
                const float w000 = w00 * mz, w001 = w00 * tz;
                const float w010 = w01 * mz, w011 = w01 * tz;
                const float w100 = w10 * mz, w101 = w10 * tz;
                const float w110 = w11 * mz, w111 = w11 * tz;

                const int b00 = (x0 * G + y0) * G;
                const int b01 = (x0 * G + y1) * G;
                const int b10 = (x1 * G + y0) * G;
                const int b11 = (x1 * G + y1) * G;

                const float dens =
                    w000 * dens_g[b00 + z0] + w001 * dens_g[b00 + z1] +
                    w010 * dens_g[b01 + z0] + w011 * dens_g[b01 + z1] +
                    w100 * dens_g[b10 + z0] + w101 * dens_g[b10 + z1] +
                    w110 * dens_g[b11 + z0] + w111 * dens_g[b11 + z1];

                const float e = __expf(dens + ACT_SHIFT);
                alpha = 1.f - rsqrtf(1.f + e);

                #pragma unroll
                for (int ch = 0; ch < 3; ++ch) {
                    const float* k0c = k0_g + ch * CHSTRIDE;
                    const float v =
                        w000 * k0c[b00 + z0] + w001 * k0c[b00 + z1] +
                        w010 * k0c[b01 + z0] + w011 * k0c[b01 + z1] +
                        w100 * k0c[b10 + z0] + w101 * k0c[b10 + z1] +
                        w110 * k0c[b11 + z0] + w111 * k0c[b11 + z1];
                    const float sg = 1.f / (1.f + __expf(-v));
                    if (ch == 0) cr = sg; else if (ch == 1) cg = sg; else cb = sg;
                }
            }
        }

        float incl = 1.f - alpha;
        #pragma unroll
        for (int off = 1; off < 64; off <<= 1) {
            const float v = __shfl_up(incl, off, 64);
            if (lane >= off) incl *= v;
        }
        float excl = __shfl_up(incl, 1, 64);
        if (lane == 0) excl = 1.f;

        const float w = alpha * T * excl;
        ar = fmaf(w, cr, ar);
        ag = fmaf(w, cg, ag);
        ab = fmaf(w, cb, ab);

        T *= __shfl(incl, 63, 64);

        if (__ballot(valid) == 0ull) break;
        if (T < 1e-5f) break;
    }

    #pragma unroll
    for (int off = 32; off > 0; off >>= 1) {
        ar += __shfl_down(ar, off, 64);
        ag += __shfl_down(ag, off, 64);
        ab += __shfl_down(ab, off, 64);
    }
    if (lane == 0) {
        out[wave * 3 + 0] = ar + T;
        out[wave * 3 + 1] = ag + T;
        out[wave * 3 + 2] = ab + T;
    }
}

extern "C" void kernel_launch(void* const* d_in, const int* in_sizes, int n_in,
                              void* d_out, int out_size, void* d_ws, size_t ws_size,
                              hipStream_t stream) {
    const float* rays_o  = (const float*)d_in[0];
    const float* rays_d  = (const float*)d_in[1];
    const float* density = (const float*)d_in[2];
    const float* k0      = (const float*)d_in[3];
    float* out = (float*)d_out;
    const int N = in_sizes[0] / 3;

    // ws layout: packed grid (16.4MB) | order[2N] | partials[2N] float4
    const size_t grid_b    = (size_t)G3 * 4;
    const size_t order_b   = (size_t)2 * N * 4;
    const size_t part_b    = (size_t)2 * N * 16;
    const size_t need = grid_b + order_b + part_b;

    if (ws_size >= need && N == MAXRAYS) {
        unsigned int* packed = (unsigned int*)d_ws;
        unsigned int* order  = (unsigned int*)((char*)d_ws + grid_b);
        float4* partials     = (float4*)((char*)d_ws + grid_b + order_b);
        const int pack_blocks = (G3 + 4095) / 4096;   // 1000
        prep_fused<<<pack_blocks + 1, 1024, 0, stream>>>(density, k0, rays_o, rays_d,
                                                         packed, order, N);
        const int rblocks = (2 * N) / 4;              // 8192, one wave per task
        dvgo_render_split<<<rblocks, 256, 0, stream>>>(rays_o, rays_d, packed, order,
                                                       partials, N);
        combine_halves<<<(N + 255) / 256, 256, 0, stream>>>(rays_o, rays_d, partials, out, N);
    } else {
        const int blocks = (N * 64 + 255) / 256;
        dvgo_render_f32<<<blocks, 256, 0, stream>>>(rays_o, rays_d, density, k0, out, N);
    }
}

// Round 13
// 111.564 us; speedup vs baseline: 1.0294x; 1.0294x over previous
//
#include <hip/hip_runtime.h>
#include <math.h>

#define G 160
#define GM1 159
#define NS 558
#define CHSTRIDE (160 * 160 * 160)
#define G3 (160 * 160 * 160)

#define DENS_SCALE (10.0f / 255.0f)
#define DENS_BIAS  (-5.0f)
#define COL_SCALE  (7.0f / 255.0f)
#define COL_BIAS   (-3.5f)

#define NBKT 1024            // half(1b) x entry/exit cell (9b)
#define MAXRAYS 16384
#define SENT 0xFFFFFFFFu

// ---------------- fused prep: block 0 sorts 2N (ray,seg) tasks, others pack grid ----------------

__device__ __forceinline__ unsigned int q8(float v, float bias, float invscale) {
    return (unsigned int)lrintf(fminf(fmaxf((v - bias) * invscale, 0.f), 255.f));
}

__device__ __forceinline__ void task_keys(
    const float* __restrict__ rays_o, const float* __restrict__ rays_d, int r,
    unsigned int& keyA, unsigned int& keyB)
{
    const float ox = rays_o[r * 3 + 0], oy = rays_o[r * 3 + 1], oz = rays_o[r * 3 + 2];
    const float dx = rays_d[r * 3 + 0], dy = rays_d[r * 3 + 1], dz = rays_d[r * 3 + 2];
    const float vx = (dx == 0.f) ? 1e-6f : dx;
    const float vy = (dy == 0.f) ? 1e-6f : dy;
    const float vz = (dz == 0.f) ? 1e-6f : dz;
    const float rax = (1.f - ox) / vx, rbx = (-1.f - ox) / vx;
    const float ray_ = (1.f - oy) / vy, rby = (-1.f - oy) / vy;
    const float raz = (1.f - oz) / vz, rbz = (-1.f - oz) / vz;
    float tmin = fmaxf(fmaxf(fminf(rax, rbx), fminf(ray_, rby)), fminf(raz, rbz));
    float tmax = fminf(fminf(fmaxf(rax, rbx), fmaxf(ray_, rby)), fmaxf(raz, rbz));
    tmin = fminf(fmaxf(tmin, 0.2f), 6.0f);
    tmax = fminf(fmaxf(tmax, 0.2f), 6.0f);
    // entry task A
    {
        const float pxr = fmaf(dx, tmin, ox);
        const float px = fminf(fmaxf(pxr, -1.f), 1.f);
        const float py = fminf(fmaxf(fmaf(dy, tmin, oy), -1.f), 1.f);
        const float pz = fminf(fmaxf(fmaf(dz, tmin, oz), -1.f), 1.f);
        const int cx = min(7, (int)((px + 1.f) * 4.f));
        const int cy = min(7, (int)((py + 1.f) * 4.f));
        const int cz = min(7, (int)((pz + 1.f) * 4.f));
        const unsigned int h = (pxr >= 0.f) ? 1u : 0u;
        keyA = (h << 9) | (unsigned int)((cx << 6) | (cy << 3) | cz);
    }
    // exit task B
    {
        const float pxr = fmaf(dx, tmax, ox);
        const float px = fminf(fmaxf(pxr, -1.f), 1.f);
        const float py = fminf(fmaxf(fmaf(dy, tmax, oy), -1.f), 1.f);
        const float pz = fminf(fmaxf(fmaf(dz, tmax, oz), -1.f), 1.f);
        const int cx = min(7, (int)((px + 1.f) * 4.f));
        const int cy = min(7, (int)((py + 1.f) * 4.f));
        const int cz = min(7, (int)((pz + 1.f) * 4.f));
        const unsigned int h = (pxr >= 0.f) ? 1u : 0u;
        keyB = (h << 9) | (unsigned int)((cx << 6) | (cy << 3) | cz);
    }
}

__global__ __launch_bounds__(1024) void prep_fused(
    const float* __restrict__ dens,
    const float* __restrict__ k0,
    const float* __restrict__ rays_o,
    const float* __restrict__ rays_d,
    unsigned int* __restrict__ packed,
    unsigned int* __restrict__ order, int N)   // order[4N]: half0 tasks at [0,2N), half1 at [2N,4N), sentinel-padded
{
    __shared__ unsigned int hist[NBKT];
    __shared__ unsigned int tmp[NBKT];

    const int tid = threadIdx.x;

    if (blockIdx.x == 0) {
        for (int i = tid; i < NBKT; i += 1024) hist[i] = 0;
        __syncthreads();
        for (int r = tid; r < N; r += 1024) {
            unsigned int ka, kb;
            task_keys(rays_o, rays_d, r, ka, kb);
            atomicAdd(&hist[ka], 1u);
            atomicAdd(&hist[kb], 1u);
        }
        __syncthreads();
        // inclusive scan of 1024 buckets (1 per thread)
        tmp[tid] = hist[tid];
        __syncthreads();
        for (int off = 1; off < NBKT; off <<= 1) {
            const unsigned int v = (tid >= off) ? tmp[tid - off] : 0u;
            __syncthreads();
            tmp[tid] += v;
            __syncthreads();
        }
        const unsigned int cnt0 = tmp[511];          // total tasks labeled half 0
        unsigned int off0 = tmp[tid] - hist[tid];    // exclusive
        if (tid >= 512) off0 += (2u * (unsigned int)N - cnt0);  // half1 region starts at 2N
        hist[tid] = off0;                            // reuse hist as scatter cursors
        // sentinel fill
        for (int i = tid; i < 4 * N; i += 1024) order[i] = SENT;
        __syncthreads();
        for (int r = tid; r < N; r += 1024) {
            unsigned int ka, kb;
            task_keys(rays_o, rays_d, r, ka, kb);
            const unsigned int pa = atomicAdd(&hist[ka], 1u);
            order[pa] = ((unsigned int)r << 1) | 0u;
            const unsigned int pb = atomicAdd(&hist[kb], 1u);
            order[pb] = ((unsigned int)r << 1) | 1u;
        }
    } else {
        // ---- pack 4 voxels/thread: {dens, k0.rgb} -> u8x4 ----
        const int base = ((blockIdx.x - 1) * 1024 + tid) * 4;
        if (base + 3 < G3) {
            const float4 d = *(const float4*)(dens + base);
            const float4 r = *(const float4*)(k0 + base);
            const float4 g = *(const float4*)(k0 + CHSTRIDE + base);
            const float4 b = *(const float4*)(k0 + 2 * CHSTRIDE + base);
            const float dis = 255.f / 10.f, cis = 255.f / 7.f;
            uint4 o;
            o.x = q8(d.x, DENS_BIAS, dis) | (q8(r.x, COL_BIAS, cis) << 8) |
                  (q8(g.x, COL_BIAS, cis) << 16) | (q8(b.x, COL_BIAS, cis) << 24);
            o.y = q8(d.y, DENS_BIAS, dis) | (q8(r.y, COL_BIAS, cis) << 8) |
                  (q8(g.y, COL_BIAS, cis) << 16) | (q8(b.y, COL_BIAS, cis) << 24);
            o.z = q8(d.z, DENS_BIAS, dis) | (q8(r.z, COL_BIAS, cis) << 8) |
                  (q8(g.z, COL_BIAS, cis) << 16) | (q8(b.z, COL_BIAS, cis) << 24);
            o.w = q8(d.w, DENS_BIAS, dis) | (q8(r.w, COL_BIAS, cis) << 8) |
                  (q8(g.w, COL_BIAS, cis) << 16) | (q8(b.w, COL_BIAS, cis) << 24);
            *(uint4*)(packed + base) = o;
        }
    }
}

// ---------------- render: per-(ray,segment) task, chunk-boundary split, R10 inner loop ----------------

__device__ __forceinline__ float ub(unsigned int q, int c) {
    return (float)((q >> (c * 8)) & 0xffu);   // v_cvt_f32_ubyte{c}
}

struct SampleData {
    unsigned int q000, q001, q010, q011, q100, q101, q110, q111;
    float w000, w001, w010, w011, w100, w101, w110, w111;
    float amask;
};

__device__ __forceinline__ SampleData fetch_sample(
    const unsigned int* __restrict__ pg,
    float ex, float ey, float ez, float gx, float gy, float gz, int s)
{
    SampleData r;
    const float sF = (float)s;
    const float fx = fmaf(gx, sF, ex);
    const float fy = fmaf(gy, sF, ey);
    const float fz = fmaf(gz, sF, ez);
    const float mn  = fminf(fminf(fx, fy), fz);
    const float mx_ = fmaxf(fmaxf(fx, fy), fz);
    r.amask = (mn >= 0.f && mx_ <= 159.f) ? 1.f : 0.f;
    const float cfx = __builtin_amdgcn_fmed3f(fx, 0.f, 159.f);
    const float cfy = __builtin_amdgcn_fmed3f(fy, 0.f, 159.f);
    const float cfz = __builtin_amdgcn_fmed3f(fz, 0.f, 159.f);
    const int x0 = (int)cfx; const float tx = cfx - (float)x0;
    const int y0 = (int)cfy; const float ty = cfy - (float)y0;
    const int z0 = (int)cfz; const float tz = cfz - (float)z0;
    const int x1 = min(x0 + 1, GM1);
    const int y1 = min(y0 + 1, GM1);
    // z1 unclamped: z0==159 => tz==0 => zero weight; 4B overrun lands in order[] (finite).
    const float mx = 1.f - tx, my = 1.f - ty, mz = 1.f - tz;
    const float w00 = mx * my, w01 = mx * ty, w10 = tx * my, w11 = tx * ty;
    r.w000 = w00 * mz; r.w001 = w00 * tz;
    r.w010 = w01 * mz; r.w011 = w01 * tz;
    r.w100 = w10 * mz; r.w101 = w10 * tz;
    r.w110 = w11 * mz; r.w111 = w11 * tz;
    const int xg0 = x0 * G, xg1 = x1 * G;
    const int i00 = (xg0 + y0) * G + z0;
    const int i01 = (xg0 + y1) * G + z0;
    const int i10 = (xg1 + y0) * G + z0;
    const int i11 = (xg1 + y1) * G + z0;
    r.q000 = pg[i00]; r.q001 = pg[i00 + 1];
    r.q010 = pg[i01]; r.q011 = pg[i01 + 1];
    r.q100 = pg[i10]; r.q101 = pg[i10 + 1];
    r.q110 = pg[i11]; r.q111 = pg[i11 + 1];
    return r;
}

__device__ __forceinline__ void composite(const SampleData& d, int lane,
    float& T, float& ar, float& ag, float& ab)
{
    const float ACT_SHIFT = -4.59511985013459f;
    float acc[4];
    #pragma unroll
    for (int ch = 0; ch < 4; ++ch) {
        acc[ch] = d.w000 * ub(d.q000, ch) + d.w001 * ub(d.q001, ch) +
                  d.w010 * ub(d.q010, ch) + d.w011 * ub(d.q011, ch) +
                  d.w100 * ub(d.q100, ch) + d.w101 * ub(d.q101, ch) +
                  d.w110 * ub(d.q110, ch) + d.w111 * ub(d.q111, ch);
    }
    const float dens = fmaf(acc[0], DENS_SCALE, DENS_BIAS);
    const float vr   = fmaf(acc[1], COL_SCALE,  COL_BIAS);
    const float vg   = fmaf(acc[2], COL_SCALE,  COL_BIAS);
    const float vb   = fmaf(acc[3], COL_SCALE,  COL_BIAS);
    const float e = __expf(dens + ACT_SHIFT);
    const float oma = __builtin_amdgcn_rsqf(1.f + e);   // 1 - alpha_raw
    const float alpha = (1.f - oma) * d.amask;
    const float cr = __builtin_amdgcn_rcpf(1.f + __expf(-vr));
    const float cg = __builtin_amdgcn_rcpf(1.f + __expf(-vg));
    const float cb = __builtin_amdgcn_rcpf(1.f + __expf(-vb));

    const float one_m_a = 1.f - alpha;    // >= 0.63 (u8 density clamp)
    float incl = one_m_a;
    #pragma unroll
    for (int off = 1; off < 64; off <<= 1) {
        const float v = __shfl_up(incl, off, 64);
        if (lane >= off) incl *= v;
    }
    const float excl = incl * __builtin_amdgcn_rcpf(one_m_a);
    const float w = alpha * T * excl;
    ar = fmaf(w, cr, ar);
    ag = fmaf(w, cg, ag);
    ab = fmaf(w, cb, ab);
    T *= __shfl(incl, 63, 64);
}

__global__ __launch_bounds__(256) void dvgo_render_seg(
    const float* __restrict__ rays_o,
    const float* __restrict__ rays_d,
    const unsigned int* __restrict__ pg,
    const unsigned int* __restrict__ order,
    float4* __restrict__ partials, int N)      // partials[seg*N + ray] = (r,g,b,T)
{
    // XCDs 0-3 -> half-0 task region, XCDs 4-7 -> half-1. 64-block chunk
    // interleave within each half for load balance. Grid = 4N/4 blocks.
    const unsigned int bid  = blockIdx.x;
    const unsigned int xcd  = bid & 7u;
    const int half          = (int)(xcd >> 2);
    const unsigned int xcdh = xcd & 3u;
    const unsigned int j    = bid >> 3;          // [0, 2N/16)
    const unsigned int cseq = j >> 6;
    const unsigned int pos  = j & 63u;
    const unsigned int bidp = (cseq * 4u + xcdh) * 64u + pos;   // [0, 2N/4)
    const int slot = (int)(bidp * 4u + (threadIdx.x >> 6));     // [0, 2N)
    const int lane = (int)(threadIdx.x & 63u);
    const unsigned int task = order[half * 2 * N + slot];
    if (task == SENT) return;
    const int ray = (int)(task >> 1);
    const int seg = (int)(task & 1u);

    const float ox = rays_o[ray * 3 + 0], oy = rays_o[ray * 3 + 1], oz = rays_o[ray * 3 + 2];
    const float dx = rays_d[ray * 3 + 0], dy = rays_d[ray * 3 + 1], dz = rays_d[ray * 3 + 2];
    const float inv_norm = __builtin_amdgcn_rsqf(dx * dx + dy * dy + dz * dz);

    const float vx = (dx == 0.f) ? 1e-6f : dx;
    const float vy = (dy == 0.f) ? 1e-6f : dy;
    const float vz = (dz == 0.f) ? 1e-6f : dz;
    const float rax = (1.f - ox) / vx, rbx = (-1.f - ox) / vx;
    const float ray_ = (1.f - oy) / vy, rby = (-1.f - oy) / vy;
    const float raz = (1.f - oz) / vz, rbz = (-1.f - oz) / vz;
    float tmin = fmaxf(fmaxf(fminf(rax, rbx), fminf(ray_, rby)), fminf(raz, rbz));
    float tmax = fminf(fminf(fmaxf(rax, rbx), fmaxf(ray_, rby)), fmaxf(raz, rbz));
    tmin = fminf(fmaxf(tmin, 0.2f), 6.0f);
    tmax = fminf(fmaxf(tmax, 0.2f), 6.0f);

    const float dt = 0.00625f * inv_norm;

    int n_samp = 0;
    if (!(tmax < tmin)) n_samp = min(NS, (int)((tmax - tmin) / dt) + 2);
    const int nch = (n_samp + 63) >> 6;

    // chunk boundary nearest the x=0 crossing (any kc in [0,nch] is correct:
    // it's only a partition point — per-sample math identical to the unsplit kernel)
    const float t_cross = (0.f - ox) / vx;
    const float sc = (t_cross - tmin) / dt;
    int kc = (int)floorf(sc * (1.f / 64.f) + 0.5f);
    kc = max(0, min(kc, nch));

    const int cb = seg ? kc : 0;
    const int ce = seg ? nch : kc;
    const int ncl = ce - cb;

    // ray fused into index space: f = fmaf(g, s, e), s absolute
    const float ex = (fmaf(dx, tmin, ox) + 1.f) * 79.5f;
    const float ey = (fmaf(dy, tmin, oy) + 1.f) * 79.5f;
    const float ez = (fmaf(dz, tmin, oz) + 1.f) * 79.5f;
    const float gx = dx * dt * 79.5f;
    const float gy = dy * dt * 79.5f;
    const float gz = dz * dt * 79.5f;

    float T = 1.f;
    float ar = 0.f, ag = 0.f, ab = 0.f;

    if (ncl > 0) {
        SampleData sd0 = fetch_sample(pg, ex, ey, ez, gx, gy, gz, (cb << 6) + lane);
        SampleData sd1;
        if (ncl > 1) sd1 = fetch_sample(pg, ex, ey, ez, gx, gy, gz, ((cb + 1) << 6) + lane);
        for (int c = 0; c < ncl; ++c) {
            SampleData sd2;
            if (c + 2 < ncl)
                sd2 = fetch_sample(pg, ex, ey, ez, gx, gy, gz, ((cb + c + 2) << 6) + lane);

            composite(sd0, lane, T, ar, ag, ab);

            sd0 = sd1;
            sd1 = sd2;
        }
    }

    #pragma unroll
    for (int off = 32; off > 0; off >>= 1) {
        ar += __shfl_down(ar, off, 64);
        ag += __shfl_down(ag, off, 64);
        ab += __shfl_down(ab, off, 64);
    }
    if (lane == 0) {
        partials[seg * N + ray] = make_float4(ar, ag, ab, T);
    }
}

// ---------------- combine: out = rgbA + TA*rgbB + TA*TB*BG  (A is always first) ----------------

__global__ __launch_bounds__(256) void combine_segs(
    const float4* __restrict__ partials,
    float* __restrict__ out, int N)
{
    const int r = blockIdx.x * 256 + threadIdx.x;
    if (r >= N) return;
    const float4 a = partials[r];         // segment A (chunks [0,kc))
    const float4 b = partials[N + r];     // segment B (chunks [kc,nch))
    out[r * 3 + 0] = a.x + a.w * b.x + a.w * b.w;
    out[r * 3 + 1] = a.y + a.w * b.y + a.w * b.w;
    out[r * 3 + 2] = a.z + a.w * b.z + a.w * b.w;
}

// ---------------- fallback: f32 4-array render (ws too small / N mismatch) ----------------

__global__ __launch_bounds__(256) void dvgo_render_f32(
    const float* __restrict__ rays_o,
    const float* __restrict__ rays_d,
    const float* __restrict__ dens_g,
    const float* __restrict__ k0_g,
    float* __restrict__ out, int N)
{
    const int wave = (int)((blockIdx.x * 256u + threadIdx.x) >> 6);
    const int lane = (int)(threadIdx.x & 63u);
    if (wave >= N) return;

    const float ox = rays_o[wave * 3 + 0], oy = rays_o[wave * 3 + 1], oz = rays_o[wave * 3 + 2];
    const float dx = rays_d[wave * 3 + 0], dy = rays_d[wave * 3 + 1], dz = rays_d[wave * 3 + 2];
    const float inv_norm = rsqrtf(dx * dx + dy * dy + dz * dz);

    const float vx = (dx == 0.f) ? 1e-6f : dx;
    const float vy = (dy == 0.f) ? 1e-6f : dy;
    const float vz = (dz == 0.f) ? 1e-6f : dz;
    const float rax = (1.f - ox) / vx, rbx = (-1.f - ox) / vx;
    const float ray_ = (1.f - oy) / vy, rby = (-1.f - oy) / vy;
    const float raz = (1.f - oz) / vz, rbz = (-1.f - oz) / vz;
    float tmin = fmaxf(fmaxf(fminf(rax, rbx), fminf(ray_, rby)), fminf(raz, rbz));
    float tmax = fminf(fminf(fmaxf(rax, rbx), fmaxf(ray_, rby)), fmaxf(raz, rbz));
    tmin = fminf(fmaxf(tmin, 0.2f), 6.0f);
    tmax = fminf(fmaxf(tmax, 0.2f), 6.0f);
    const bool ray_oob = (tmax < tmin);

    const float dt = 0.00625f * inv_norm;
    const float ACT_SHIFT = -4.59511985013459f;

    float T = 1.f;
    float ar = 0.f, ag = 0.f, ab = 0.f;

    for (int s0 = 0; s0 < NS; s0 += 64) {
        const int s = s0 + lane;
        float alpha = 0.f, cr = 0.f, cg = 0.f, cb = 0.f;
        bool valid = false;
        if (!ray_oob && s < NS) {
            const float t = tmin + dt * (float)s;
            const float px = fmaf(dx, t, ox);
            const float py = fmaf(dy, t, oy);
            const float pz = fmaf(dz, t, oz);
            if (px >= -1.f && px <= 1.f && py >= -1.f && py <= 1.f &&
                pz >= -1.f && pz <= 1.f) {
                valid = true;
                const float fx = (px + 1.f) * 79.5f;
                const float fy = (py + 1.f) * 79.5f;
                const float fz = (pz + 1.f) * 79.5f;
                int x0 = (int)fx; const float tx = fx - (float)x0;
                int y0 = (int)fy; const float ty = fy - (float)y0;
                int z0 = (int)fz; const float tz = fz - (float)z0;
                x0 = min(x0, GM1); y0 = min(y0, GM1); z0 = min(z0, GM1);
                const int x1 = min(x0 + 1, GM1);
                const int y1 = min(y0 + 1, GM1);
                const int z1 = min(z0 + 1, GM1);

                const float mx = 1.f - tx, my = 1.f - ty, mz = 1.f - tz;
                const float w00 = mx * my, w01 = mx * ty, w10 = tx * my, w11 = tx * ty;
                const float w000 = w00 * mz, w001 = w00 * tz;
                const float w010 = w01 * mz, w011 = w01 * tz;
                const float w100 = w10 * mz, w101 = w10 * tz;
                const float w110 = w11 * mz, w111 = w11 * tz;

                const int b00 = (x0 * G + y0) * G;
                const int b01 = (x0 * G + y1) * G;
                const int b10 = (x1 * G + y0) * G;
                const int b11 = (x1 * G + y1) * G;

                const float dens =
                    w000 * dens_g[b00 + z0] + w001 * dens_g[b00 + z1] +
                    w010 * dens_g[b01 + z0] + w011 * dens_g[b01 + z1] +
                    w100 * dens_g[b10 + z0] + w101 * dens_g[b10 + z1] +
                    w110 * dens_g[b11 + z0] + w111 * dens_g[b11 + z1];

                const float e = __expf(dens + ACT_SHIFT);
                alpha = 1.f - rsqrtf(1.f + e);

                #pragma unroll
                for (int ch = 0; ch < 3; ++ch) {
                    const float* k0c = k0_g + ch * CHSTRIDE;
                    const float v =
                        w000 * k0c[b00 + z0] + w001 * k0c[b00 + z1] +
                        w010 * k0c[b01 + z0] + w011 * k0c[b01 + z1] +
                        w100 * k0c[b10 + z0] + w101 * k0c[b10 + z1] +
                        w110 * k0c[b11 + z0] + w111 * k0c[b11 + z1];
                    const float sg = 1.f / (1.f + __expf(-v));
                    if (ch == 0) cr = sg; else if (ch == 1) cg = sg; else cb = sg;
                }
            }
        }

        float incl = 1.f - alpha;
        #pragma unroll
        for (int off = 1; off < 64; off <<= 1) {
            const float v = __shfl_up(incl, off, 64);
            if (lane >= off) incl *= v;
        }
        float excl = __shfl_up(incl, 1, 64);
        if (lane == 0) excl = 1.f;

        const float w = alpha * T * excl;
        ar = fmaf(w, cr, ar);
        ag = fmaf(w, cg, ag);
        ab = fmaf(w, cb, ab);

        T *= __shfl(incl, 63, 64);

        if (__ballot(valid) == 0ull) break;
        if (T < 1e-5f) break;
    }

    #pragma unroll
    for (int off = 32; off > 0; off >>= 1) {
        ar += __shfl_down(ar, off, 64);
        ag += __shfl_down(ag, off, 64);
        ab += __shfl_down(ab, off, 64);
    }
    if (lane == 0) {
        out[wave * 3 + 0] = ar + T;
        out[wave * 3 + 1] = ag + T;
        out[wave * 3 + 2] = ab + T;
    }
}

extern "C" void kernel_launch(void* const* d_in, const int* in_sizes, int n_in,
                              void* d_out, int out_size, void* d_ws, size_t ws_size,
                              hipStream_t stream) {
    const float* rays_o  = (const float*)d_in[0];
    const float* rays_d  = (const float*)d_in[1];
    const float* density = (const float*)d_in[2];
    const float* k0      = (const float*)d_in[3];
    float* out = (float*)d_out;
    const int N = in_sizes[0] / 3;

    // ws layout: packed grid (16.4MB) | order[4N] | partials[2N] float4
    const size_t grid_b  = (size_t)G3 * 4;
    const size_t order_b = (size_t)4 * N * 4;
    const size_t part_b  = (size_t)2 * N * 16;
    const size_t need = grid_b + order_b + part_b;

    if (ws_size >= need && N == MAXRAYS) {
        unsigned int* packed = (unsigned int*)d_ws;
        unsigned int* order  = (unsigned int*)((char*)d_ws + grid_b);
        float4* partials     = (float4*)((char*)d_ws + grid_b + order_b);
        const int pack_blocks = (G3 + 4095) / 4096;   // 1000
        prep_fused<<<pack_blocks + 1, 1024, 0, stream>>>(density, k0, rays_o, rays_d,
                                                         packed, order, N);
        const int rblocks = (4 * N) / 4;              // 16384 blocks, 4 task-slots each
        dvgo_render_seg<<<rblocks, 256, 0, stream>>>(rays_o, rays_d, packed, order,
                                                     partials, N);
        combine_segs<<<(N + 255) / 256, 256, 0, stream>>>(partials, out, N);
    } else {
        const int blocks = (N * 64 + 255) / 256;
        dvgo_render_f32<<<blocks, 256, 0, stream>>>(rays_o, rays_d, density, k0, out, N);
    }
}

// Round 14
// 85.304 us; speedup vs baseline: 1.3463x; 1.3078x over previous
//
#include <hip/hip_runtime.h>
#include <math.h>

#define G 160
#define GM1 159
#define NS 558
#define CHSTRIDE (160 * 160 * 160)
#define G3 (160 * 160 * 160)

#define DENS_SCALE (10.0f / 255.0f)
#define DENS_BIAS  (-5.0f)
#define COL_SCALE  (7.0f / 255.0f)
#define COL_BIAS   (-3.5f)

#define NBUCKET 512
#define SORT_BLOCKS 8
#define RPB 2048
#define MAXRAYS 16384

// ---------------- fused prep: blocks 0..7 sort ray slices, rest pack grid ----------------

__device__ __forceinline__ unsigned int q8(float v, float bias, float invscale) {
    return (unsigned int)lrintf(fminf(fmaxf((v - bias) * invscale, 0.f), 255.f));
}

__global__ __launch_bounds__(1024) void prep_fused(
    const float* __restrict__ dens,
    const float* __restrict__ k0,
    const float* __restrict__ rays_o,
    const float* __restrict__ rays_d,
    unsigned int* __restrict__ packed,
    unsigned int* __restrict__ order, int N)
{
    __shared__ unsigned short skeys[RPB];      // 4 KB
    __shared__ unsigned int hist[NBUCKET];     // 2 KB
    __shared__ unsigned int tmp[NBUCKET];      // 2 KB
    __shared__ unsigned int offs[NBUCKET];     // 2 KB

    const int tid = threadIdx.x;

    if (blockIdx.x < SORT_BLOCKS) {
        // ---- counting sort of rays [rbase, rbase+RPB) by bbox entry cell (8x8x8) ----
        // 8 independent slice-sorts run in parallel; per-slice cell coherence is
        // what the render's 256-ray XCD windows need (global order not required).
        const int rbase  = blockIdx.x * RPB;
        const int rcount = min(RPB, N - rbase);
        if (rcount <= 0) return;
        for (int i = tid; i < NBUCKET; i += 1024) hist[i] = 0;
        __syncthreads();
        for (int i = tid; i < rcount; i += 1024) {
            const int r = rbase + i;
            const float ox = rays_o[r * 3 + 0], oy = rays_o[r * 3 + 1], oz = rays_o[r * 3 + 2];
            const float dx = rays_d[r * 3 + 0], dy = rays_d[r * 3 + 1], dz = rays_d[r * 3 + 2];
            const float vx = (dx == 0.f) ? 1e-6f : dx;
            const float vy = (dy == 0.f) ? 1e-6f : dy;
            const float vz = (dz == 0.f) ? 1e-6f : dz;
            const float rax = (1.f - ox) / vx, rbx = (-1.f - ox) / vx;
            const float ray_ = (1.f - oy) / vy, rby = (-1.f - oy) / vy;
            const float raz = (1.f - oz) / vz, rbz = (-1.f - oz) / vz;
            float tmin = fmaxf(fmaxf(fminf(rax, rbx), fminf(ray_, rby)), fminf(raz, rbz));
            tmin = fminf(fmaxf(tmin, 0.2f), 6.0f);
            const float px = fminf(fmaxf(fmaf(dx, tmin, ox), -1.f), 1.f);
            const float py = fminf(fmaxf(fmaf(dy, tmin, oy), -1.f), 1.f);
            const float pz = fminf(fmaxf(fmaf(dz, tmin, oz), -1.f), 1.f);
            const int cx = min(7, (int)((px + 1.f) * 4.f));
            const int cy = min(7, (int)((py + 1.f) * 4.f));
            const int cz = min(7, (int)((pz + 1.f) * 4.f));
            const unsigned int key = (unsigned int)((cx << 6) | (cy << 3) | cz);
            skeys[i] = (unsigned short)key;
            atomicAdd(&hist[key], 1u);
        }
        __syncthreads();
        if (tid < NBUCKET) tmp[tid] = hist[tid];
        __syncthreads();
        for (int off = 1; off < NBUCKET; off <<= 1) {
            unsigned int v = 0;
            if (tid < NBUCKET && tid >= off) v = tmp[tid - off];
            __syncthreads();
            if (tid < NBUCKET) tmp[tid] += v;
            __syncthreads();
        }
        if (tid < NBUCKET) offs[tid] = tmp[tid] - hist[tid];   // exclusive
        __syncthreads();
        for (int i = tid; i < rcount; i += 1024) {
            const unsigned int pos = atomicAdd(&offs[skeys[i]], 1u);
            order[rbase + pos] = (unsigned int)(rbase + i);
        }
    } else {
        // ---- pack 4 voxels/thread: {dens, k0.rgb} -> u8x4 ----
        const int base = ((blockIdx.x - SORT_BLOCKS) * 1024 + tid) * 4;
        if (base + 3 < G3) {
            const float4 d = *(const float4*)(dens + base);
            const float4 r = *(const float4*)(k0 + base);
            const float4 g = *(const float4*)(k0 + CHSTRIDE + base);
            const float4 b = *(const float4*)(k0 + 2 * CHSTRIDE + base);
            const float dis = 255.f / 10.f, cis = 255.f / 7.f;
            uint4 o;
            o.x = q8(d.x, DENS_BIAS, dis) | (q8(r.x, COL_BIAS, cis) << 8) |
                  (q8(g.x, COL_BIAS, cis) << 16) | (q8(b.x, COL_BIAS, cis) << 24);
            o.y = q8(d.y, DENS_BIAS, dis) | (q8(r.y, COL_BIAS, cis) << 8) |
                  (q8(g.y, COL_BIAS, cis) << 16) | (q8(b.y, COL_BIAS, cis) << 24);
            o.z = q8(d.z, DENS_BIAS, dis) | (q8(r.z, COL_BIAS, cis) << 8) |
                  (q8(g.z, COL_BIAS, cis) << 16) | (q8(b.z, COL_BIAS, cis) << 24);
            o.w = q8(d.w, DENS_BIAS, dis) | (q8(r.w, COL_BIAS, cis) << 8) |
                  (q8(g.w, COL_BIAS, cis) << 16) | (q8(b.w, COL_BIAS, cis) << 24);
            *(uint4*)(packed + base) = o;
        }
    }
}

// ---------------- render: 2-deep pipelined (R10 structure), branchless sampling ----------------

__device__ __forceinline__ float ub(unsigned int q, int c) {
    return (float)((q >> (c * 8)) & 0xffu);   // v_cvt_f32_ubyte{c}
}

struct SampleData {
    unsigned int q000, q001, q010, q011, q100, q101, q110, q111;
    float w000, w001, w010, w011, w100, w101, w110, w111;
    float amask;
};

__device__ __forceinline__ SampleData fetch_sample(
    const unsigned int* __restrict__ pg,
    float ex, float ey, float ez, float gx, float gy, float gz, int s)
{
    SampleData r;
    const float sF = (float)s;
    const float fx = fmaf(gx, sF, ex);
    const float fy = fmaf(gy, sF, ey);
    const float fz = fmaf(gz, sF, ez);
    const float mn  = fminf(fminf(fx, fy), fz);
    const float mx_ = fmaxf(fmaxf(fx, fy), fz);
    r.amask = (mn >= 0.f && mx_ <= 159.f) ? 1.f : 0.f;
    const float cfx = __builtin_amdgcn_fmed3f(fx, 0.f, 159.f);
    const float cfy = __builtin_amdgcn_fmed3f(fy, 0.f, 159.f);
    const float cfz = __builtin_amdgcn_fmed3f(fz, 0.f, 159.f);
    const int x0 = (int)cfx; const float tx = cfx - (float)x0;
    const int y0 = (int)cfy; const float ty = cfy - (float)y0;
    const int z0 = (int)cfz; const float tz = cfz - (float)z0;
    const int x1 = min(x0 + 1, GM1);
    const int y1 = min(y0 + 1, GM1);
    // z1 unclamped: z0==159 => tz==0 => zero weight; 4B overrun lands in order[] (finite).
    const float mx = 1.f - tx, my = 1.f - ty, mz = 1.f - tz;
    const float w00 = mx * my, w01 = mx * ty, w10 = tx * my, w11 = tx * ty;
    r.w000 = w00 * mz; r.w001 = w00 * tz;
    r.w010 = w01 * mz; r.w011 = w01 * tz;
    r.w100 = w10 * mz; r.w101 = w10 * tz;
    r.w110 = w11 * mz; r.w111 = w11 * tz;
    const int xg0 = x0 * G, xg1 = x1 * G;
    const int i00 = (xg0 + y0) * G + z0;
    const int i01 = (xg0 + y1) * G + z0;
    const int i10 = (xg1 + y0) * G + z0;
    const int i11 = (xg1 + y1) * G + z0;
    r.q000 = pg[i00]; r.q001 = pg[i00 + 1];
    r.q010 = pg[i01]; r.q011 = pg[i01 + 1];
    r.q100 = pg[i10]; r.q101 = pg[i10 + 1];
    r.q110 = pg[i11]; r.q111 = pg[i11 + 1];
    return r;
}

__device__ __forceinline__ void composite(const SampleData& d, int lane,
    float& T, float& ar, float& ag, float& ab)
{
    const float ACT_SHIFT = -4.59511985013459f;
    float acc[4];
    #pragma unroll
    for (int ch = 0; ch < 4; ++ch) {
        acc[ch] = d.w000 * ub(d.q000, ch) + d.w001 * ub(d.q001, ch) +
                  d.w010 * ub(d.q010, ch) + d.w011 * ub(d.q011, ch) +
                  d.w100 * ub(d.q100, ch) + d.w101 * ub(d.q101, ch) +
                  d.w110 * ub(d.q110, ch) + d.w111 * ub(d.q111, ch);
    }
    const float dens = fmaf(acc[0], DENS_SCALE, DENS_BIAS);
    const float vr   = fmaf(acc[1], COL_SCALE,  COL_BIAS);
    const float vg   = fmaf(acc[2], COL_SCALE,  COL_BIAS);
    const float vb   = fmaf(acc[3], COL_SCALE,  COL_BIAS);
    const float e = __expf(dens + ACT_SHIFT);
    const float oma = __builtin_amdgcn_rsqf(1.f + e);   // 1 - alpha_raw
    const float alpha = (1.f - oma) * d.amask;
    const float cr = __builtin_amdgcn_rcpf(1.f + __expf(-vr));
    const float cg = __builtin_amdgcn_rcpf(1.f + __expf(-vg));
    const float cb = __builtin_amdgcn_rcpf(1.f + __expf(-vb));

    // inclusive prefix product of (1-alpha); excl = incl * rcp(1-alpha)
    // (safe: u8 density clamp => alpha <= 0.37 => 1-alpha >= 0.63)
    const float one_m_a = 1.f - alpha;
    float incl = one_m_a;
    #pragma unroll
    for (int off = 1; off < 64; off <<= 1) {
        const float v = __shfl_up(incl, off, 64);
        if (lane >= off) incl *= v;
    }
    const float excl = incl * __builtin_amdgcn_rcpf(one_m_a);
    const float w = alpha * T * excl;
    ar = fmaf(w, cr, ar);
    ag = fmaf(w, cg, ag);
    ab = fmaf(w, cb, ab);
    T *= __shfl(incl, 63, 64);
}

__global__ __launch_bounds__(256) void dvgo_render_u8(
    const float* __restrict__ rays_o,
    const float* __restrict__ rays_d,
    const unsigned int* __restrict__ pg,
    const unsigned int* __restrict__ order,   // may be null -> identity
    float* __restrict__ out, int N)
{
    // XCD swizzle, 64-block (256-ray) chunks: XCD k processes chunks
    // {k, k+8, ...} of the sorted ray list -> per-XCD L2 locality windows
    // + ray-length balance (each XCD samples the whole sorted spectrum).
    unsigned int bid = blockIdx.x;
    const unsigned int nblk = gridDim.x;
    if ((nblk & 511u) == 0u) {
        const unsigned int xcd  = bid & 7u;
        const unsigned int step = bid >> 3;
        const unsigned int cseq = step >> 6;
        const unsigned int pos  = step & 63u;
        bid = (cseq * 8u + xcd) * 64u + pos;
    } else if ((nblk & 7u) == 0u) {
        bid = (bid & 7u) * (nblk >> 3) + (bid >> 3);
    }
    const int slot = (int)(bid * 4 + (threadIdx.x >> 6));
    const int lane = (int)(threadIdx.x & 63u);
    if (slot >= N) return;
    const int wave = order ? (int)order[slot] : slot;

    const float ox = rays_o[wave * 3 + 0], oy = rays_o[wave * 3 + 1], oz = rays_o[wave * 3 + 2];
    const float dx = rays_d[wave * 3 + 0], dy = rays_d[wave * 3 + 1], dz = rays_d[wave * 3 + 2];
    const float inv_norm = __builtin_amdgcn_rsqf(dx * dx + dy * dy + dz * dz);

    const float vx = (dx == 0.f) ? 1e-6f : dx;
    const float vy = (dy == 0.f) ? 1e-6f : dy;
    const float vz = (dz == 0.f) ? 1e-6f : dz;
    const float rax = (1.f - ox) / vx, rbx = (-1.f - ox) / vx;
    const float ray_ = (1.f - oy) / vy, rby = (-1.f - oy) / vy;
    const float raz = (1.f - oz) / vz, rbz = (-1.f - oz) / vz;
    float tmin = fmaxf(fmaxf(fminf(rax, rbx), fminf(ray_, rby)), fminf(raz, rbz));
    float tmax = fminf(fminf(fmaxf(rax, rbx), fmaxf(ray_, rby)), fmaxf(raz, rbz));
    tmin = fminf(fmaxf(tmin, 0.2f), 6.0f);
    tmax = fminf(fmaxf(tmax, 0.2f), 6.0f);

    const float dt = 0.00625f * inv_norm;

    // ray fused into index space: f = fmaf(g, s, e)
    const float ex = (fmaf(dx, tmin, ox) + 1.f) * 79.5f;
    const float ey = (fmaf(dy, tmin, oy) + 1.f) * 79.5f;
    const float ez = (fmaf(dz, tmin, oz) + 1.f) * 79.5f;
    const float gx = dx * dt * 79.5f;
    const float gy = dy * dt * 79.5f;
    const float gz = dz * dt * 79.5f;

    int n_samp = 0;
    if (!(tmax < tmin)) n_samp = min(NS, (int)((tmax - tmin) / dt) + 2);
    const int n_chunks = (n_samp + 63) >> 6;

    float T = 1.f;
    float ar = 0.f, ag = 0.f, ab = 0.f;

    if (n_chunks > 0) {
        // 2-deep software pipeline (compiler-scheduled, no spills).
        SampleData sd0 = fetch_sample(pg, ex, ey, ez, gx, gy, gz, lane);
        SampleData sd1;
        if (n_chunks > 1) sd1 = fetch_sample(pg, ex, ey, ez, gx, gy, gz, 64 + lane);
        for (int c = 0; c < n_chunks; ++c) {
            SampleData sd2;
            if (c + 2 < n_chunks)
                sd2 = fetch_sample(pg, ex, ey, ez, gx, gy, gz, ((c + 2) << 6) + lane);

            composite(sd0, lane, T, ar, ag, ab);

            sd0 = sd1;
            sd1 = sd2;
        }
    }

    #pragma unroll
    for (int off = 32; off > 0; off >>= 1) {
        ar += __shfl_down(ar, off, 64);
        ag += __shfl_down(ag, off, 64);
        ab += __shfl_down(ab, off, 64);
    }
    if (lane == 0) {
        out[wave * 3 + 0] = ar + T;
        out[wave * 3 + 1] = ag + T;
        out[wave * 3 + 2] = ab + T;
    }
}

// ---------------- fallback: f32 4-array render (ws too small) ----------------

__global__ __launch_bounds__(256) void dvgo_render_f32(
    const float* __restrict__ rays_o,
    const float* __restrict__ rays_d,
    const float* __restrict__ dens_g,
    const float* __restrict__ k0_g,
    float* __restrict__ out, int N)
{
    const int wave = (int)((blockIdx.x * 256u + threadIdx.x) >> 6);
    const int lane = (int)(threadIdx.x & 63u);
    if (wave >= N) return;

    const float ox = rays_o[wave * 3 + 0], oy = rays_o[wave * 3 + 1], oz = rays_o[wave * 3 + 2];
    const float dx = rays_d[wave * 3 + 0], dy = rays_d[wave * 3 + 1], dz = rays_d[wave * 3 + 2];
    const float inv_norm = rsqrtf(dx * dx + dy * dy + dz * dz);

    const float vx = (dx == 0.f) ? 1e-6f : dx;
    const float vy = (dy == 0.f) ? 1e-6f : dy;
    const float vz = (dz == 0.f) ? 1e-6f : dz;
    const float rax = (1.f - ox) / vx, rbx = (-1.f - ox) / vx;
    const float ray_ = (1.f - oy) / vy, rby = (-1.f - oy) / vy;
    const float raz = (1.f - oz) / vz, rbz = (-1.f - oz) / vz;
    float tmin = fmaxf(fmaxf(fminf(rax, rbx), fminf(ray_, rby)), fminf(raz, rbz));
    float tmax = fminf(fminf(fmaxf(rax, rbx), fmaxf(ray_, rby)), fmaxf(raz, rbz));
    tmin = fminf(fmaxf(tmin, 0.2f), 6.0f);
    tmax = fminf(fmaxf(tmax, 0.2f), 6.0f);
    const bool ray_oob = (tmax < tmin);

    const float dt = 0.00625f * inv_norm;
    const float ACT_SHIFT = -4.59511985013459f;

    float T = 1.f;
    float ar = 0.f, ag = 0.f, ab = 0.f;

    for (int s0 = 0; s0 < NS; s0 += 64) {
        const int s = s0 + lane;
        float alpha = 0.f, cr = 0.f, cg = 0.f, cb = 0.f;
        bool valid = false;
        if (!ray_oob && s < NS) {
            const float t = tmin + dt * (float)s;
            const float px = fmaf(dx, t, ox);
            const float py = fmaf(dy, t, oy);
            const float pz = fmaf(dz, t, oz);
            if (px >= -1.f && px <= 1.f && py >= -1.f && py <= 1.f &&
                pz >= -1.f && pz <= 1.f) {
                valid = true;
                const float fx = (px + 1.f) * 79.5f;
                const float fy = (py + 1.f) * 79.5f;
                const float fz = (pz + 1.f) * 79.5f;
                int x0 = (int)fx; const float tx = fx - (float)x0;
                int y0 = (int)fy; const float ty = fy - (float)y0;
                int z0 = (int)fz; const float tz = fz - (float)z0;
                x0 = min(x0, GM1); y0 = min(y0, GM1); z0 = min(z0, GM1);
                const int x1 = min(x0 + 1, GM1);
                const int y1 = min(y0 + 1, GM1);
                const int z1 = min(z0 + 1, GM1);

                const float mx = 1.f - tx, my = 1.f - ty, mz = 1.f - tz;
                const float w00 = mx * my, w01 = mx * ty, w10 = tx * my, w11 = tx * ty;
                const float w000 = w00 * mz, w001 = w00 * tz;
                const float w010 = w01 * mz, w011 = w01 * tz;
                const float w100 = w10 * mz, w101 = w10 * tz;
                const float w110 = w11 * mz, w111 = w11 * tz;

                const int b00 = (x0 * G + y0) * G;
                const int b01 = (x0 * G + y1) * G;
                const int b10 = (x1 * G + y0) * G;
                const int b11 = (x1 * G + y1) * G;

                const float dens =
                    w000 * dens_g[b00 + z0] + w001 * dens_g[b00 + z1] +
                    w010 * dens_g[b01 + z0] + w011 * dens_g[b01 + z1] +
                    w100 * dens_g[b10 + z0] + w101 * dens_g[b10 + z1] +
                    w110 * dens_g[b11 + z0] + w111 * dens_g[b11 + z1];

                const float e = __expf(dens + ACT_SHIFT);
                alpha = 1.f - rsqrtf(1.f + e);

                #pragma unroll
                for (int ch = 0; ch < 3; ++ch) {
                    const float* k0c = k0_g + ch * CHSTRIDE;
                    const float v =
                        w000 * k0c[b00 + z0] + w001 * k0c[b00 + z1] +
                        w010 * k0c[b01 + z0] + w011 * k0c[b01 + z1] +
                        w100 * k0c[b10 + z0] + w101 * k0c[b10 + z1] +
                        w110 * k0c[b11 + z0] + w111 * k0c[b11 + z1];
                    const float sg = 1.f / (1.f + __expf(-v));
                    if (ch == 0) cr = sg; else if (ch == 1) cg = sg; else cb = sg;
                }
            }
        }

        float incl = 1.f - alpha;
        #pragma unroll
        for (int off = 1; off < 64; off <<= 1) {
            const float v = __shfl_up(incl, off, 64);
            if (lane >= off) incl *= v;
        }
        float excl = __shfl_up(incl, 1, 64);
        if (lane == 0) excl = 1.f;

        const float w = alpha * T * excl;
        ar = fmaf(w, cr, ar);
        ag = fmaf(w, cg, ag);
        ab = fmaf(w, cb, ab);

        T *= __shfl(incl, 63, 64);

        if (__ballot(valid) == 0ull) break;
        if (T < 1e-5f) break;
    }

    #pragma unroll
    for (int off = 32; off > 0; off >>= 1) {
        ar += __shfl_down(ar, off, 64);
        ag += __shfl_down(ag, off, 64);
        ab += __shfl_down(ab, off, 64);
    }
    if (lane == 0) {
        out[wave * 3 + 0] = ar + T;
        out[wave * 3 + 1] = ag + T;
        out[wave * 3 + 2] = ab + T;
    }
}

extern "C" void kernel_launch(void* const* d_in, const int* in_sizes, int n_in,
                              void* d_out, int out_size, void* d_ws, size_t ws_size,
                              hipStream_t stream) {
    const float* rays_o  = (const float*)d_in[0];
    const float* rays_d  = (const float*)d_in[1];
    const float* density = (const float*)d_in[2];
    const float* k0      = (const float*)d_in[3];
    float* out = (float*)d_out;
    const int N = in_sizes[0] / 3;

    const int blocks = (N * 64 + 255) / 256;

    // ws layout: packed grid | order[N]  (order doubles as overrun pad for z-pair loads)
    const size_t grid_b = (size_t)G3 * 4;
    const size_t need   = grid_b + (size_t)N * 4;

    if (ws_size >= need && N == MAXRAYS) {
        unsigned int* packed = (unsigned int*)d_ws;
        unsigned int* order  = (unsigned int*)((char*)d_ws + grid_b);
        const int pack_blocks = (G3 + 4095) / 4096;   // 1000
        prep_fused<<<pack_blocks + SORT_BLOCKS, 1024, 0, stream>>>(density, k0, rays_o, rays_d,
                                                                   packed, order, N);
        dvgo_render_u8<<<blocks, 256, 0, stream>>>(rays_o, rays_d, packed, order, out, N);
    } else {
        dvgo_render_f32<<<blocks, 256, 0, stream>>>(rays_o, rays_d, density, k0, out, N);
    }
}

// Round 15
// 80.851 us; speedup vs baseline: 1.4204x; 1.0551x over previous
//
#include <hip/hip_runtime.h>
#include <math.h>

#define G 160
#define GM1 159
#define NS 558
#define CHSTRIDE (160 * 160 * 160)
#define G3 (160 * 160 * 160)

#define DENS_SCALE (10.0f / 255.0f)
#define DENS_BIAS  (-5.0f)
#define COL_SCALE  (7.0f / 255.0f)
#define COL_BIAS   (-3.5f)

#define NBUCKET 512
#define SORT_BLOCKS 2
#define RPB 8192
#define MAXRAYS 16384

// ---------------- fused prep: blocks 0..1 sort ray halves, rest pack grid ----------------

__device__ __forceinline__ unsigned int q8(float v, float bias, float invscale) {
    return (unsigned int)lrintf(fminf(fmaxf((v - bias) * invscale, 0.f), 255.f));
}

__global__ __launch_bounds__(1024) void prep_fused(
    const float* __restrict__ dens,
    const float* __restrict__ k0,
    const float* __restrict__ rays_o,
    const float* __restrict__ rays_d,
    unsigned int* __restrict__ packed,
    unsigned int* __restrict__ order, int N)
{
    __shared__ unsigned short skeys[RPB];      // 16 KB
    __shared__ unsigned int hist[NBUCKET];     // 2 KB
    __shared__ unsigned int tmp[NBUCKET];      // 2 KB
    __shared__ unsigned int offs[NBUCKET];     // 2 KB

    const int tid = threadIdx.x;

    if (blockIdx.x < SORT_BLOCKS) {
        // ---- counting sort of rays [rbase, rbase+RPB) by bbox entry cell (8x8x8) ----
        // 2 parallel half-sorts: 16 rays/bucket -> a 256-ray render window spans
        // ~16 cells (vs 8 for a global sort, 64 for 8-way slices). Each sort
        // block's runtime ~= pack's BW floor, so the sort hides under pack.
        const int rbase  = blockIdx.x * RPB;
        const int rcount = min(RPB, N - rbase);
        if (rcount <= 0) return;
        for (int i = tid; i < NBUCKET; i += 1024) hist[i] = 0;
        __syncthreads();
        for (int i = tid; i < rcount; i += 1024) {
            const int r = rbase + i;
            const float ox = rays_o[r * 3 + 0], oy = rays_o[r * 3 + 1], oz = rays_o[r * 3 + 2];
            const float dx = rays_d[r * 3 + 0], dy = rays_d[r * 3 + 1], dz = rays_d[r * 3 + 2];
            const float vx = (dx == 0.f) ? 1e-6f : dx;
            const float vy = (dy == 0.f) ? 1e-6f : dy;
            const float vz = (dz == 0.f) ? 1e-6f : dz;
            const float rax = (1.f - ox) / vx, rbx = (-1.f - ox) / vx;
            const float ray_ = (1.f - oy) / vy, rby = (-1.f - oy) / vy;
            const float raz = (1.f - oz) / vz, rbz = (-1.f - oz) / vz;
            float tmin = fmaxf(fmaxf(fminf(rax, rbx), fminf(ray_, rby)), fminf(raz, rbz));
            tmin = fminf(fmaxf(tmin, 0.2f), 6.0f);
            const float px = fminf(fmaxf(fmaf(dx, tmin, ox), -1.f), 1.f);
            const float py = fminf(fmaxf(fmaf(dy, tmin, oy), -1.f), 1.f);
            const float pz = fminf(fmaxf(fmaf(dz, tmin, oz), -1.f), 1.f);
            const int cx = min(7, (int)((px + 1.f) * 4.f));
            const int cy = min(7, (int)((py + 1.f) * 4.f));
            const int cz = min(7, (int)((pz + 1.f) * 4.f));
            const unsigned int key = (unsigned int)((cx << 6) | (cy << 3) | cz);
            skeys[i] = (unsigned short)key;
            atomicAdd(&hist[key], 1u);
        }
        __syncthreads();
        if (tid < NBUCKET) tmp[tid] = hist[tid];
        __syncthreads();
        for (int off = 1; off < NBUCKET; off <<= 1) {
            unsigned int v = 0;
            if (tid < NBUCKET && tid >= off) v = tmp[tid - off];
            __syncthreads();
            if (tid < NBUCKET) tmp[tid] += v;
            __syncthreads();
        }
        if (tid < NBUCKET) offs[tid] = tmp[tid] - hist[tid];   // exclusive
        __syncthreads();
        for (int i = tid; i < rcount; i += 1024) {
            const unsigned int pos = atomicAdd(&offs[skeys[i]], 1u);
            order[rbase + pos] = (unsigned int)(rbase + i);
        }
    } else {
        // ---- pack 4 voxels/thread: {dens, k0.rgb} -> u8x4 ----
        const int base = ((blockIdx.x - SORT_BLOCKS) * 1024 + tid) * 4;
        if (base + 3 < G3) {
            const float4 d = *(const float4*)(dens + base);
            const float4 r = *(const float4*)(k0 + base);
            const float4 g = *(const float4*)(k0 + CHSTRIDE + base);
            const float4 b = *(const float4*)(k0 + 2 * CHSTRIDE + base);
            const float dis = 255.f / 10.f, cis = 255.f / 7.f;
            uint4 o;
            o.x = q8(d.x, DENS_BIAS, dis) | (q8(r.x, COL_BIAS, cis) << 8) |
                  (q8(g.x, COL_BIAS, cis) << 16) | (q8(b.x, COL_BIAS, cis) << 24);
            o.y = q8(d.y, DENS_BIAS, dis) | (q8(r.y, COL_BIAS, cis) << 8) |
                  (q8(g.y, COL_BIAS, cis) << 16) | (q8(b.y, COL_BIAS, cis) << 24);
            o.z = q8(d.z, DENS_BIAS, dis) | (q8(r.z, COL_BIAS, cis) << 8) |
                  (q8(g.z, COL_BIAS, cis) << 16) | (q8(b.z, COL_BIAS, cis) << 24);
            o.w = q8(d.w, DENS_BIAS, dis) | (q8(r.w, COL_BIAS, cis) << 8) |
                  (q8(g.w, COL_BIAS, cis) << 16) | (q8(b.w, COL_BIAS, cis) << 24);
            *(uint4*)(packed + base) = o;
        }
    }
}

// ---------------- render: 2-deep pipelined (R10 structure), branchless sampling ----------------

__device__ __forceinline__ float ub(unsigned int q, int c) {
    return (float)((q >> (c * 8)) & 0xffu);   // v_cvt_f32_ubyte{c}
}

struct SampleData {
    unsigned int q000, q001, q010, q011, q100, q101, q110, q111;
    float w000, w001, w010, w011, w100, w101, w110, w111;
    float amask;
};

__device__ __forceinline__ SampleData fetch_sample(
    const unsigned int* __restrict__ pg,
    float ex, float ey, float ez, float gx, float gy, float gz, int s)
{
    SampleData r;
    const float sF = (float)s;
    const float fx = fmaf(gx, sF, ex);
    const float fy = fmaf(gy, sF, ey);
    const float fz = fmaf(gz, sF, ez);
    const float mn  = fminf(fminf(fx, fy), fz);
    const float mx_ = fmaxf(fmaxf(fx, fy), fz);
    r.amask = (mn >= 0.f && mx_ <= 159.f) ? 1.f : 0.f;
    const float cfx = __builtin_amdgcn_fmed3f(fx, 0.f, 159.f);
    const float cfy = __builtin_amdgcn_fmed3f(fy, 0.f, 159.f);
    const float cfz = __builtin_amdgcn_fmed3f(fz, 0.f, 159.f);
    const int x0 = (int)cfx; const float tx = cfx - (float)x0;
    const int y0 = (int)cfy; const float ty = cfy - (float)y0;
    const int z0 = (int)cfz; const float tz = cfz - (float)z0;
    const int x1 = min(x0 + 1, GM1);
    const int y1 = min(y0 + 1, GM1);
    // z1 unclamped: z0==159 => tz==0 => zero weight; 4B overrun lands in order[] (finite).
    const float mx = 1.f - tx, my = 1.f - ty, mz = 1.f - tz;
    const float w00 = mx * my, w01 = mx * ty, w10 = tx * my, w11 = tx * ty;
    r.w000 = w00 * mz; r.w001 = w00 * tz;
    r.w010 = w01 * mz; r.w011 = w01 * tz;
    r.w100 = w10 * mz; r.w101 = w10 * tz;
    r.w110 = w11 * mz; r.w111 = w11 * tz;
    const int xg0 = x0 * G, xg1 = x1 * G;
    const int i00 = (xg0 + y0) * G + z0;
    const int i01 = (xg0 + y1) * G + z0;
    const int i10 = (xg1 + y0) * G + z0;
    const int i11 = (xg1 + y1) * G + z0;
    r.q000 = pg[i00]; r.q001 = pg[i00 + 1];
    r.q010 = pg[i01]; r.q011 = pg[i01 + 1];
    r.q100 = pg[i10]; r.q101 = pg[i10 + 1];
    r.q110 = pg[i11]; r.q111 = pg[i11 + 1];
    return r;
}

__device__ __forceinline__ void composite(const SampleData& d, int lane,
    float& T, float& ar, float& ag, float& ab)
{
    const float ACT_SHIFT = -4.59511985013459f;
    float acc[4];
    #pragma unroll
    for (int ch = 0; ch < 4; ++ch) {
        acc[ch] = d.w000 * ub(d.q000, ch) + d.w001 * ub(d.q001, ch) +
                  d.w010 * ub(d.q010, ch) + d.w011 * ub(d.q011, ch) +
                  d.w100 * ub(d.q100, ch) + d.w101 * ub(d.q101, ch) +
                  d.w110 * ub(d.q110, ch) + d.w111 * ub(d.q111, ch);
    }
    const float dens = fmaf(acc[0], DENS_SCALE, DENS_BIAS);
    const float vr   = fmaf(acc[1], COL_SCALE,  COL_BIAS);
    const float vg   = fmaf(acc[2], COL_SCALE,  COL_BIAS);
    const float vb   = fmaf(acc[3], COL_SCALE,  COL_BIAS);
    const float e = __expf(dens + ACT_SHIFT);
    const float oma = __builtin_amdgcn_rsqf(1.f + e);   // 1 - alpha_raw
    const float alpha = (1.f - oma) * d.amask;
    const float cr = __builtin_amdgcn_rcpf(1.f + __expf(-vr));
    const float cg = __builtin_amdgcn_rcpf(1.f + __expf(-vg));
    const float cb = __builtin_amdgcn_rcpf(1.f + __expf(-vb));

    // inclusive prefix product of (1-alpha); excl = incl * rcp(1-alpha)
    // (safe: u8 density clamp => alpha <= 0.37 => 1-alpha >= 0.63)
    const float one_m_a = 1.f - alpha;
    float incl = one_m_a;
    #pragma unroll
    for (int off = 1; off < 64; off <<= 1) {
        const float v = __shfl_up(incl, off, 64);
        if (lane >= off) incl *= v;
    }
    const float excl = incl * __builtin_amdgcn_rcpf(one_m_a);
    const float w = alpha * T * excl;
    ar = fmaf(w, cr, ar);
    ag = fmaf(w, cg, ag);
    ab = fmaf(w, cb, ab);
    T *= __shfl(incl, 63, 64);
}

__global__ __launch_bounds__(256) void dvgo_render_u8(
    const float* __restrict__ rays_o,
    const float* __restrict__ rays_d,
    const unsigned int* __restrict__ pg,
    const unsigned int* __restrict__ order,   // may be null -> identity
    float* __restrict__ out, int N)
{
    // XCD swizzle, 64-block (256-ray) chunks: XCD k processes chunks
    // {k, k+8, ...} of the sorted ray list -> per-XCD L2 locality windows
    // + ray-length balance (each XCD samples the whole sorted spectrum).
    unsigned int bid = blockIdx.x;
    const unsigned int nblk = gridDim.x;
    if ((nblk & 511u) == 0u) {
        const unsigned int xcd  = bid & 7u;
        const unsigned int step = bid >> 3;
        const unsigned int cseq = step >> 6;
        const unsigned int pos  = step & 63u;
        bid = (cseq * 8u + xcd) * 64u + pos;
    } else if ((nblk & 7u) == 0u) {
        bid = (bid & 7u) * (nblk >> 3) + (bid >> 3);
    }
    const int slot = (int)(bid * 4 + (threadIdx.x >> 6));
    const int lane = (int)(threadIdx.x & 63u);
    if (slot >= N) return;
    const int wave = order ? (int)order[slot] : slot;

    const float ox = rays_o[wave * 3 + 0], oy = rays_o[wave * 3 + 1], oz = rays_o[wave * 3 + 2];
    const float dx = rays_d[wave * 3 + 0], dy = rays_d[wave * 3 + 1], dz = rays_d[wave * 3 + 2];
    const float inv_norm = __builtin_amdgcn_rsqf(dx * dx + dy * dy + dz * dz);

    const float vx = (dx == 0.f) ? 1e-6f : dx;
    const float vy = (dy == 0.f) ? 1e-6f : dy;
    const float vz = (dz == 0.f) ? 1e-6f : dz;
    const float rax = (1.f - ox) / vx, rbx = (-1.f - ox) / vx;
    const float ray_ = (1.f - oy) / vy, rby = (-1.f - oy) / vy;
    const float raz = (1.f - oz) / vz, rbz = (-1.f - oz) / vz;
    float tmin = fmaxf(fmaxf(fminf(rax, rbx), fminf(ray_, rby)), fminf(raz, rbz));
    float tmax = fminf(fminf(fmaxf(rax, rbx), fmaxf(ray_, rby)), fmaxf(raz, rbz));
    tmin = fminf(fmaxf(tmin, 0.2f), 6.0f);
    tmax = fminf(fmaxf(tmax, 0.2f), 6.0f);

    const float dt = 0.00625f * inv_norm;

    // ray fused into index space: f = fmaf(g, s, e)
    const float ex = (fmaf(dx, tmin, ox) + 1.f) * 79.5f;
    const float ey = (fmaf(dy, tmin, oy) + 1.f) * 79.5f;
    const float ez = (fmaf(dz, tmin, oz) + 1.f) * 79.5f;
    const float gx = dx * dt * 79.5f;
    const float gy = dy * dt * 79.5f;
    const float gz = dz * dt * 79.5f;

    int n_samp = 0;
    if (!(tmax < tmin)) n_samp = min(NS, (int)((tmax - tmin) / dt) + 2);
    const int n_chunks = (n_samp + 63) >> 6;

    float T = 1.f;
    float ar = 0.f, ag = 0.f, ab = 0.f;

    if (n_chunks > 0) {
        // 2-deep software pipeline (compiler-scheduled, no spills).
        SampleData sd0 = fetch_sample(pg, ex, ey, ez, gx, gy, gz, lane);
        SampleData sd1;
        if (n_chunks > 1) sd1 = fetch_sample(pg, ex, ey, ez, gx, gy, gz, 64 + lane);
        for (int c = 0; c < n_chunks; ++c) {
            SampleData sd2;
            if (c + 2 < n_chunks)
                sd2 = fetch_sample(pg, ex, ey, ez, gx, gy, gz, ((c + 2) << 6) + lane);

            composite(sd0, lane, T, ar, ag, ab);

            sd0 = sd1;
            sd1 = sd2;
        }
    }

    #pragma unroll
    for (int off = 32; off > 0; off >>= 1) {
        ar += __shfl_down(ar, off, 64);
        ag += __shfl_down(ag, off, 64);
        ab += __shfl_down(ab, off, 64);
    }
    if (lane == 0) {
        out[wave * 3 + 0] = ar + T;
        out[wave * 3 + 1] = ag + T;
        out[wave * 3 + 2] = ab + T;
    }
}

// ---------------- fallback: f32 4-array render (ws too small) ----------------

__global__ __launch_bounds__(256) void dvgo_render_f32(
    const float* __restrict__ rays_o,
    const float* __restrict__ rays_d,
    const float* __restrict__ dens_g,
    const float* __restrict__ k0_g,
    float* __restrict__ out, int N)
{
    const int wave = (int)((blockIdx.x * 256u + threadIdx.x) >> 6);
    const int lane = (int)(threadIdx.x & 63u);
    if (wave >= N) return;

    const float ox = rays_o[wave * 3 + 0], oy = rays_o[wave * 3 + 1], oz = rays_o[wave * 3 + 2];
    const float dx = rays_d[wave * 3 + 0], dy = rays_d[wave * 3 + 1], dz = rays_d[wave * 3 + 2];
    const float inv_norm = rsqrtf(dx * dx + dy * dy + dz * dz);

    const float vx = (dx == 0.f) ? 1e-6f : dx;
    const float vy = (dy == 0.f) ? 1e-6f : dy;
    const float vz = (dz == 0.f) ? 1e-6f : dz;
    const float rax = (1.f - ox) / vx, rbx = (-1.f - ox) / vx;
    const float ray_ = (1.f - oy) / vy, rby = (-1.f - oy) / vy;
    const float raz = (1.f - oz) / vz, rbz = (-1.f - oz) / vz;
    float tmin = fmaxf(fmaxf(fminf(rax, rbx), fminf(ray_, rby)), fminf(raz, rbz));
    float tmax = fminf(fminf(fmaxf(rax, rbx), fmaxf(ray_, rby)), fmaxf(raz, rbz));
    tmin = fminf(fmaxf(tmin, 0.2f), 6.0f);
    tmax = fminf(fmaxf(tmax, 0.2f), 6.0f);
    const bool ray_oob = (tmax < tmin);

    const float dt = 0.00625f * inv_norm;
    const float ACT_SHIFT = -4.59511985013459f;

    float T = 1.f;
    float ar = 0.f, ag = 0.f, ab = 0.f;

    for (int s0 = 0; s0 < NS; s0 += 64) {
        const int s = s0 + lane;
        float alpha = 0.f, cr = 0.f, cg = 0.f, cb = 0.f;
        bool valid = false;
        if (!ray_oob && s < NS) {
            const float t = tmin + dt * (float)s;
            const float px = fmaf(dx, t, ox);
            const float py = fmaf(dy, t, oy);
            const float pz = fmaf(dz, t, oz);
            if (px >= -1.f && px <= 1.f && py >= -1.f && py <= 1.f &&
                pz >= -1.f && pz <= 1.f) {
                valid = true;
                const float fx = (px + 1.f) * 79.5f;
                const float fy = (py + 1.f) * 79.5f;
                const float fz = (pz + 1.f) * 79.5f;
                int x0 = (int)fx; const float tx = fx - (float)x0;
                int y0 = (int)fy; const float ty = fy - (float)y0;
                int z0 = (int)fz; const float tz = fz - (float)z0;
                x0 = min(x0, GM1); y0 = min(y0, GM1); z0 = min(z0, GM1);
                const int x1 = min(x0 + 1, GM1);
                const int y1 = min(y0 + 1, GM1);
                const int z1 = min(z0 + 1, GM1);

                const float mx = 1.f - tx, my = 1.f - ty, mz = 1.f - tz;
                const float w00 = mx * my, w01 = mx * ty, w10 = tx * my, w11 = tx * ty;
                const float w000 = w00 * mz, w001 = w00 * tz;
                const float w010 = w01 * mz, w011 = w01 * tz;
                const float w100 = w10 * mz, w101 = w10 * tz;
                const float w110 = w11 * mz, w111 = w11 * tz;

                const int b00 = (x0 * G + y0) * G;
                const int b01 = (x0 * G + y1) * G;
                const int b10 = (x1 * G + y0) * G;
                const int b11 = (x1 * G + y1) * G;

                const float dens =
                    w000 * dens_g[b00 + z0] + w001 * dens_g[b00 + z1] +
                    w010 * dens_g[b01 + z0] + w011 * dens_g[b01 + z1] +
                    w100 * dens_g[b10 + z0] + w101 * dens_g[b10 + z1] +
                    w110 * dens_g[b11 + z0] + w111 * dens_g[b11 + z1];

                const float e = __expf(dens + ACT_SHIFT);
                alpha = 1.f - rsqrtf(1.f + e);

                #pragma unroll
                for (int ch = 0; ch < 3; ++ch) {
                    const float* k0c = k0_g + ch * CHSTRIDE;
                    const float v =
                        w000 * k0c[b00 + z0] + w001 * k0c[b00 + z1] +
                        w010 * k0c[b01 + z0] + w011 * k0c[b01 + z1] +
                        w100 * k0c[b10 + z0] + w101 * k0c[b10 + z1] +
                        w110 * k0c[b11 + z0] + w111 * k0c[b11 + z1];
                    const float sg = 1.f / (1.f + __expf(-v));
                    if (ch == 0) cr = sg; else if (ch == 1) cg = sg; else cb = sg;
                }
            }
        }

        float incl = 1.f - alpha;
        #pragma unroll
        for (int off = 1; off < 64; off <<= 1) {
            const float v = __shfl_up(incl, off, 64);
            if (lane >= off) incl *= v;
        }
        float excl = __shfl_up(incl, 1, 64);
        if (lane == 0) excl = 1.f;

        const float w = alpha * T * excl;
        ar = fmaf(w, cr, ar);
        ag = fmaf(w, cg, ag);
        ab = fmaf(w, cb, ab);

        T *= __shfl(incl, 63, 64);

        if (__ballot(valid) == 0ull) break;
        if (T < 1e-5f) break;
    }

    #pragma unroll
    for (int off = 32; off > 0; off >>= 1) {
        ar += __shfl_down(ar, off, 64);
        ag += __shfl_down(ag, off, 64);
        ab += __shfl_down(ab, off, 64);
    }
    if (lane == 0) {
        out[wave * 3 + 0] = ar + T;
        out[wave * 3 + 1] = ag + T;
        out[wave * 3 + 2] = ab + T;
    }
}

extern "C" void kernel_launch(void* const* d_in, const int* in_sizes, int n_in,
                              void* d_out, int out_size, void* d_ws, size_t ws_size,
                              hipStream_t stream) {
    const float* rays_o  = (const float*)d_in[0];
    const float* rays_d  = (const float*)d_in[1];
    const float* density = (const float*)d_in[2];
    const float* k0      = (const float*)d_in[3];
    float* out = (float*)d_out;
    const int N = in_sizes[0] / 3;

    const int blocks = (N * 64 + 255) / 256;

    // ws layout: packed grid | order[N]  (order doubles as overrun pad for z-pair loads)
    const size_t grid_b = (size_t)G3 * 4;
    const size_t need   = grid_b + (size_t)N * 4;

    if (ws_size >= need && N == MAXRAYS) {
        unsigned int* packed = (unsigned int*)d_ws;
        unsigned int* order  = (unsigned int*)((char*)d_ws + grid_b);
        const int pack_blocks = (G3 + 4095) / 4096;   // 1000
        prep_fused<<<pack_blocks + SORT_BLOCKS, 1024, 0, stream>>>(density, k0, rays_o, rays_d,
                                                                   packed, order, N);
        dvgo_render_u8<<<blocks, 256, 0, stream>>>(rays_o, rays_d, packed, order, out, N);
    } else {
        dvgo_render_f32<<<blocks, 256, 0, stream>>>(rays_o, rays_d, density, k0, out, N);
    }
}

// Round 16
// 80.193 us; speedup vs baseline: 1.4321x; 1.0082x over previous
//
#include <hip/hip_runtime.h>
#include <math.h>

#define G 160
#define GM1 159
#define NS 558
#define CHSTRIDE (160 * 160 * 160)
#define G3 (160 * 160 * 160)

#define DENS_SCALE (10.0f / 255.0f)
#define DENS_BIAS  (-5.0f)
#define COL_SCALE  (7.0f / 255.0f)
#define COL_BIAS   (-3.5f)

#define NBUCKET 512
#define SORT_BLOCKS 2
#define RPB 8192
#define MAXRAYS 16384

// ---------------- fused prep: blocks 0..1 sort ray halves, rest pack grid ----------------

__device__ __forceinline__ unsigned int q8(float v, float bias, float invscale) {
    return (unsigned int)lrintf(fminf(fmaxf((v - bias) * invscale, 0.f), 255.f));
}

__global__ __launch_bounds__(1024) void prep_fused(
    const float* __restrict__ dens,
    const float* __restrict__ k0,
    const float* __restrict__ rays_o,
    const float* __restrict__ rays_d,
    unsigned int* __restrict__ packed,
    unsigned int* __restrict__ order, int N)
{
    __shared__ unsigned short skeys[RPB];      // 16 KB
    __shared__ unsigned int hist[NBUCKET];     // 2 KB
    __shared__ unsigned int tmp[NBUCKET];      // 2 KB
    __shared__ unsigned int offs[NBUCKET];     // 2 KB

    const int tid = threadIdx.x;

    if (blockIdx.x < SORT_BLOCKS) {
        // ---- counting sort of rays [rbase, rbase+RPB) by bbox entry cell (8x8x8) ----
        // Two parallel half-sorts; the render rank-interleaves the halves, which
        // recovers global-sort window quality (same cell CDF in both halves).
        const int rbase  = blockIdx.x * RPB;
        const int rcount = min(RPB, N - rbase);
        if (rcount <= 0) return;
        for (int i = tid; i < NBUCKET; i += 1024) hist[i] = 0;
        __syncthreads();
        for (int i = tid; i < rcount; i += 1024) {
            const int r = rbase + i;
            const float ox = rays_o[r * 3 + 0], oy = rays_o[r * 3 + 1], oz = rays_o[r * 3 + 2];
            const float dx = rays_d[r * 3 + 0], dy = rays_d[r * 3 + 1], dz = rays_d[r * 3 + 2];
            const float vx = (dx == 0.f) ? 1e-6f : dx;
            const float vy = (dy == 0.f) ? 1e-6f : dy;
            const float vz = (dz == 0.f) ? 1e-6f : dz;
            const float rax = (1.f - ox) / vx, rbx = (-1.f - ox) / vx;
            const float ray_ = (1.f - oy) / vy, rby = (-1.f - oy) / vy;
            const float raz = (1.f - oz) / vz, rbz = (-1.f - oz) / vz;
            float tmin = fmaxf(fmaxf(fminf(rax, rbx), fminf(ray_, rby)), fminf(raz, rbz));
            tmin = fminf(fmaxf(tmin, 0.2f), 6.0f);
            const float px = fminf(fmaxf(fmaf(dx, tmin, ox), -1.f), 1.f);
            const float py = fminf(fmaxf(fmaf(dy, tmin, oy), -1.f), 1.f);
            const float pz = fminf(fmaxf(fmaf(dz, tmin, oz), -1.f), 1.f);
            const int cx = min(7, (int)((px + 1.f) * 4.f));
            const int cy = min(7, (int)((py + 1.f) * 4.f));
            const int cz = min(7, (int)((pz + 1.f) * 4.f));
            const unsigned int key = (unsigned int)((cx << 6) | (cy << 3) | cz);
            skeys[i] = (unsigned short)key;
            atomicAdd(&hist[key], 1u);
        }
        __syncthreads();
        if (tid < NBUCKET) tmp[tid] = hist[tid];
        __syncthreads();
        for (int off = 1; off < NBUCKET; off <<= 1) {
            unsigned int v = 0;
            if (tid < NBUCKET && tid >= off) v = tmp[tid - off];
            __syncthreads();
            if (tid < NBUCKET) tmp[tid] += v;
            __syncthreads();
        }
        if (tid < NBUCKET) offs[tid] = tmp[tid] - hist[tid];   // exclusive
        __syncthreads();
        for (int i = tid; i < rcount; i += 1024) {
            const unsigned int pos = atomicAdd(&offs[skeys[i]], 1u);
            order[rbase + pos] = (unsigned int)(rbase + i);
        }
    } else {
        // ---- pack 4 voxels/thread: {dens, k0.rgb} -> u8x4 ----
        const int base = ((blockIdx.x - SORT_BLOCKS) * 1024 + tid) * 4;
        if (base + 3 < G3) {
            const float4 d = *(const float4*)(dens + base);
            const float4 r = *(const float4*)(k0 + base);
            const float4 g = *(const float4*)(k0 + CHSTRIDE + base);
            const float4 b = *(const float4*)(k0 + 2 * CHSTRIDE + base);
            const float dis = 255.f / 10.f, cis = 255.f / 7.f;
            uint4 o;
            o.x = q8(d.x, DENS_BIAS, dis) | (q8(r.x, COL_BIAS, cis) << 8) |
                  (q8(g.x, COL_BIAS, cis) << 16) | (q8(b.x, COL_BIAS, cis) << 24);
            o.y = q8(d.y, DENS_BIAS, dis) | (q8(r.y, COL_BIAS, cis) << 8) |
                  (q8(g.y, COL_BIAS, cis) << 16) | (q8(b.y, COL_BIAS, cis) << 24);
            o.z = q8(d.z, DENS_BIAS, dis) | (q8(r.z, COL_BIAS, cis) << 8) |
                  (q8(g.z, COL_BIAS, cis) << 16) | (q8(b.z, COL_BIAS, cis) << 24);
            o.w = q8(d.w, DENS_BIAS, dis) | (q8(r.w, COL_BIAS, cis) << 8) |
                  (q8(g.w, COL_BIAS, cis) << 16) | (q8(b.w, COL_BIAS, cis) << 24);
            *(uint4*)(packed + base) = o;
        }
    }
}

// ---------------- render: 2-deep pipelined (R10 structure), branchless sampling ----------------

__device__ __forceinline__ float ub(unsigned int q, int c) {
    return (float)((q >> (c * 8)) & 0xffu);   // v_cvt_f32_ubyte{c}
}

struct SampleData {
    unsigned int q000, q001, q010, q011, q100, q101, q110, q111;
    float w000, w001, w010, w011, w100, w101, w110, w111;
    float amask;
};

__device__ __forceinline__ SampleData fetch_sample(
    const unsigned int* __restrict__ pg,
    float ex, float ey, float ez, float gx, float gy, float gz, int s)
{
    SampleData r;
    const float sF = (float)s;
    const float fx = fmaf(gx, sF, ex);
    const float fy = fmaf(gy, sF, ey);
    const float fz = fmaf(gz, sF, ez);
    const float mn  = fminf(fminf(fx, fy), fz);
    const float mx_ = fmaxf(fmaxf(fx, fy), fz);
    r.amask = (mn >= 0.f && mx_ <= 159.f) ? 1.f : 0.f;
    const float cfx = __builtin_amdgcn_fmed3f(fx, 0.f, 159.f);
    const float cfy = __builtin_amdgcn_fmed3f(fy, 0.f, 159.f);
    const float cfz = __builtin_amdgcn_fmed3f(fz, 0.f, 159.f);
    const int x0 = (int)cfx; const float tx = cfx - (float)x0;
    const int y0 = (int)cfy; const float ty = cfy - (float)y0;
    const int z0 = (int)cfz; const float tz = cfz - (float)z0;
    const int x1 = min(x0 + 1, GM1);
    const int y1 = min(y0 + 1, GM1);
    // z1 unclamped: z0==159 => tz==0 => zero weight; 4B overrun lands in order[] (finite).
    const float mx = 1.f - tx, my = 1.f - ty, mz = 1.f - tz;
    const float w00 = mx * my, w01 = mx * ty, w10 = tx * my, w11 = tx * ty;
    r.w000 = w00 * mz; r.w001 = w00 * tz;
    r.w010 = w01 * mz; r.w011 = w01 * tz;
    r.w100 = w10 * mz; r.w101 = w10 * tz;
    r.w110 = w11 * mz; r.w111 = w11 * tz;
    const int xg0 = x0 * G, xg1 = x1 * G;
    const int i00 = (xg0 + y0) * G + z0;
    const int i01 = (xg0 + y1) * G + z0;
    const int i10 = (xg1 + y0) * G + z0;
    const int i11 = (xg1 + y1) * G + z0;
    r.q000 = pg[i00]; r.q001 = pg[i00 + 1];
    r.q010 = pg[i01]; r.q011 = pg[i01 + 1];
    r.q100 = pg[i10]; r.q101 = pg[i10 + 1];
    r.q110 = pg[i11]; r.q111 = pg[i11 + 1];
    return r;
}

__device__ __forceinline__ void composite(const SampleData& d, int lane,
    float& T, float& ar, float& ag, float& ab)
{
    const float ACT_SHIFT = -4.59511985013459f;
    float acc[4];
    #pragma unroll
    for (int ch = 0; ch < 4; ++ch) {
        acc[ch] = d.w000 * ub(d.q000, ch) + d.w001 * ub(d.q001, ch) +
                  d.w010 * ub(d.q010, ch) + d.w011 * ub(d.q011, ch) +
                  d.w100 * ub(d.q100, ch) + d.w101 * ub(d.q101, ch) +
                  d.w110 * ub(d.q110, ch) + d.w111 * ub(d.q111, ch);
    }
    const float dens = fmaf(acc[0], DENS_SCALE, DENS_BIAS);
    const float vr   = fmaf(acc[1], COL_SCALE,  COL_BIAS);
    const float vg   = fmaf(acc[2], COL_SCALE,  COL_BIAS);
    const float vb   = fmaf(acc[3], COL_SCALE,  COL_BIAS);
    const float e = __expf(dens + ACT_SHIFT);
    const float oma = __builtin_amdgcn_rsqf(1.f + e);   // 1 - alpha_raw
    const float alpha = (1.f - oma) * d.amask;
    const float cr = __builtin_amdgcn_rcpf(1.f + __expf(-vr));
    const float cg = __builtin_amdgcn_rcpf(1.f + __expf(-vg));
    const float cb = __builtin_amdgcn_rcpf(1.f + __expf(-vb));

    // inclusive prefix product of (1-alpha); excl = incl * rcp(1-alpha)
    // (safe: u8 density clamp => alpha <= 0.37 => 1-alpha >= 0.63)
    const float one_m_a = 1.f - alpha;
    float incl = one_m_a;
    #pragma unroll
    for (int off = 1; off < 64; off <<= 1) {
        const float v = __shfl_up(incl, off, 64);
        if (lane >= off) incl *= v;
    }
    const float excl = incl * __builtin_amdgcn_rcpf(one_m_a);
    const float w = alpha * T * excl;
    ar = fmaf(w, cr, ar);
    ag = fmaf(w, cg, ag);
    ab = fmaf(w, cb, ab);
    T *= __shfl(incl, 63, 64);
}

__global__ __launch_bounds__(256) void dvgo_render_u8(
    const float* __restrict__ rays_o,
    const float* __restrict__ rays_d,
    const unsigned int* __restrict__ pg,
    const unsigned int* __restrict__ order,   // may be null -> identity
    float* __restrict__ out, int N)
{
    // XCD swizzle, 64-block (256-ray) chunks: XCD k processes chunks
    // {k, k+8, ...} of the sorted ray list -> per-XCD L2 locality windows
    // + ray-length balance (each XCD samples the whole sorted spectrum).
    unsigned int bid = blockIdx.x;
    const unsigned int nblk = gridDim.x;
    if ((nblk & 511u) == 0u) {
        const unsigned int xcd  = bid & 7u;
        const unsigned int step = bid >> 3;
        const unsigned int cseq = step >> 6;
        const unsigned int pos  = step & 63u;
        bid = (cseq * 8u + xcd) * 64u + pos;
    } else if ((nblk & 7u) == 0u) {
        bid = (bid & 7u) * (nblk >> 3) + (bid >> 3);
    }
    const int slot = (int)(bid * 4 + (threadIdx.x >> 6));
    const int lane = (int)(threadIdx.x & 63u);
    if (slot >= N) return;
    // Rank-interleave the two sorted halves: slot -> (half = slot&1, rank = slot>>1).
    // Same-rank rays in the two halves lie in ~the same cell (identical cell CDFs),
    // so a 256-slot window covers ~8 cells with 256 rays == global-sort quality.
    int oidx = slot;
    if (N == MAXRAYS) oidx = ((slot & 1) << 13) | (slot >> 1);
    const int wave = order ? (int)order[oidx] : slot;

    const float ox = rays_o[wave * 3 + 0], oy = rays_o[wave * 3 + 1], oz = rays_o[wave * 3 + 2];
    const float dx = rays_d[wave * 3 + 0], dy = rays_d[wave * 3 + 1], dz = rays_d[wave * 3 + 2];
    const float inv_norm = __builtin_amdgcn_rsqf(dx * dx + dy * dy + dz * dz);

    const float vx = (dx == 0.f) ? 1e-6f : dx;
    const float vy = (dy == 0.f) ? 1e-6f : dy;
    const float vz = (dz == 0.f) ? 1e-6f : dz;
    const float rax = (1.f - ox) / vx, rbx = (-1.f - ox) / vx;
    const float ray_ = (1.f - oy) / vy, rby = (-1.f - oy) / vy;
    const float raz = (1.f - oz) / vz, rbz = (-1.f - oz) / vz;
    float tmin = fmaxf(fmaxf(fminf(rax, rbx), fminf(ray_, rby)), fminf(raz, rbz));
    float tmax = fminf(fminf(fmaxf(rax, rbx), fmaxf(ray_, rby)), fmaxf(raz, rbz));
    tmin = fminf(fmaxf(tmin, 0.2f), 6.0f);
    tmax = fminf(fmaxf(tmax, 0.2f), 6.0f);

    const float dt = 0.00625f * inv_norm;

    // ray fused into index space: f = fmaf(g, s, e)
    const float ex = (fmaf(dx, tmin, ox) + 1.f) * 79.5f;
    const float ey = (fmaf(dy, tmin, oy) + 1.f) * 79.5f;
    const float ez = (fmaf(dz, tmin, oz) + 1.f) * 79.5f;
    const float gx = dx * dt * 79.5f;
    const float gy = dy * dt * 79.5f;
    const float gz = dz * dt * 79.5f;

    int n_samp = 0;
    if (!(tmax < tmin)) n_samp = min(NS, (int)((tmax - tmin) / dt) + 2);
    const int n_chunks = (n_samp + 63) >> 6;

    float T = 1.f;
    float ar = 0.f, ag = 0.f, ab = 0.f;

    if (n_chunks > 0) {
        // 2-deep software pipeline (compiler-scheduled, no spills).
        SampleData sd0 = fetch_sample(pg, ex, ey, ez, gx, gy, gz, lane);
        SampleData sd1;
        if (n_chunks > 1) sd1 = fetch_sample(pg, ex, ey, ez, gx, gy, gz, 64 + lane);
        for (int c = 0; c < n_chunks; ++c) {
            SampleData sd2;
            if (c + 2 < n_chunks)
                sd2 = fetch_sample(pg, ex, ey, ez, gx, gy, gz, ((c + 2) << 6) + lane);

            composite(sd0, lane, T, ar, ag, ab);

            sd0 = sd1;
            sd1 = sd2;
        }
    }

    #pragma unroll
    for (int off = 32; off > 0; off >>= 1) {
        ar += __shfl_down(ar, off, 64);
        ag += __shfl_down(ag, off, 64);
        ab += __shfl_down(ab, off, 64);
    }
    if (lane == 0) {
        out[wave * 3 + 0] = ar + T;
        out[wave * 3 + 1] = ag + T;
        out[wave * 3 + 2] = ab + T;
    }
}

// ---------------- fallback: f32 4-array render (ws too small) ----------------

__global__ __launch_bounds__(256) void dvgo_render_f32(
    const float* __restrict__ rays_o,
    const float* __restrict__ rays_d,
    const float* __restrict__ dens_g,
    const float* __restrict__ k0_g,
    float* __restrict__ out, int N)
{
    const int wave = (int)((blockIdx.x * 256u + threadIdx.x) >> 6);
    const int lane = (int)(threadIdx.x & 63u);
    if (wave >= N) return;

    const float ox = rays_o[wave * 3 + 0], oy = rays_o[wave * 3 + 1], oz = rays_o[wave * 3 + 2];
    const float dx = rays_d[wave * 3 + 0], dy = rays_d[wave * 3 + 1], dz = rays_d[wave * 3 + 2];
    const float inv_norm = rsqrtf(dx * dx + dy * dy + dz * dz);

    const float vx = (dx == 0.f) ? 1e-6f : dx;
    const float vy = (dy == 0.f) ? 1e-6f : dy;
    const float vz = (dz == 0.f) ? 1e-6f : dz;
    const float rax = (1.f - ox) / vx, rbx = (-1.f - ox) / vx;
    const float ray_ = (1.f - oy) / vy, rby = (-1.f - oy) / vy;
    const float raz = (1.f - oz) / vz, rbz = (-1.f - oz) / vz;
    float tmin = fmaxf(fmaxf(fminf(rax, rbx), fminf(ray_, rby)), fminf(raz, rbz));
    float tmax = fminf(fminf(fmaxf(rax, rbx), fmaxf(ray_, rby)), fmaxf(raz, rbz));
    tmin = fminf(fmaxf(tmin, 0.2f), 6.0f);
    tmax = fminf(fmaxf(tmax, 0.2f), 6.0f);
    const bool ray_oob = (tmax < tmin);

    const float dt = 0.00625f * inv_norm;
    const float ACT_SHIFT = -4.59511985013459f;

    float T = 1.f;
    float ar = 0.f, ag = 0.f, ab = 0.f;

    for (int s0 = 0; s0 < NS; s0 += 64) {
        const int s = s0 + lane;
        float alpha = 0.f, cr = 0.f, cg = 0.f, cb = 0.f;
        bool valid = false;
        if (!ray_oob && s < NS) {
            const float t = tmin + dt * (float)s;
            const float px = fmaf(dx, t, ox);
            const float py = fmaf(dy, t, oy);
            const float pz = fmaf(dz, t, oz);
            if (px >= -1.f && px <= 1.f && py >= -1.f && py <= 1.f &&
                pz >= -1.f && pz <= 1.f) {
                valid = true;
                const float fx = (px + 1.f) * 79.5f;
                const float fy = (py + 1.f) * 79.5f;
                const float fz = (pz + 1.f) * 79.5f;
                int x0 = (int)fx; const float tx = fx - (float)x0;
                int y0 = (int)fy; const float ty = fy - (float)y0;
                int z0 = (int)fz; const float tz = fz - (float)z0;
                x0 = min(x0, GM1); y0 = min(y0, GM1); z0 = min(z0, GM1);
                const int x1 = min(x0 + 1, GM1);
                const int y1 = min(y0 + 1, GM1);
                const int z1 = min(z0 + 1, GM1);

                const float mx = 1.f - tx, my = 1.f - ty, mz = 1.f - tz;
                const float w00 = mx * my, w01 = mx * ty, w10 = tx * my, w11 = tx * ty;
                const float w000 = w00 * mz, w001 = w00 * tz;
                const float w010 = w01 * mz, w011 = w01 * tz;
                const float w100 = w10 * mz, w101 = w10 * tz;
                const float w110 = w11 * mz, w111 = w11 * tz;

                const int b00 = (x0 * G + y0) * G;
                const int b01 = (x0 * G + y1) * G;
                const int b10 = (x1 * G + y0) * G;
                const int b11 = (x1 * G + y1) * G;

                const float dens =
                    w000 * dens_g[b00 + z0] + w001 * dens_g[b00 + z1] +
                    w010 * dens_g[b01 + z0] + w011 * dens_g[b01 + z1] +
                    w100 * dens_g[b10 + z0] + w101 * dens_g[b10 + z1] +
                    w110 * dens_g[b11 + z0] + w111 * dens_g[b11 + z1];

                const float e = __expf(dens + ACT_SHIFT);
                alpha = 1.f - rsqrtf(1.f + e);

                #pragma unroll
                for (int ch = 0; ch < 3; ++ch) {
                    const float* k0c = k0_g + ch * CHSTRIDE;
                    const float v =
                        w000 * k0c[b00 + z0] + w001 * k0c[b00 + z1] +
                        w010 * k0c[b01 + z0] + w011 * k0c[b01 + z1] +
                        w100 * k0c[b10 + z0] + w101 * k0c[b10 + z1] +
                        w110 * k0c[b11 + z0] + w111 * k0c[b11 + z1];
                    const float sg = 1.f / (1.f + __expf(-v));
                    if (ch == 0) cr = sg; else if (ch == 1) cg = sg; else cb = sg;
                }
            }
        }

        float incl = 1.f - alpha;
        #pragma unroll
        for (int off = 1; off < 64; off <<= 1) {
            const float v = __shfl_up(incl, off, 64);
            if (lane >= off) incl *= v;
        }
        float excl = __shfl_up(incl, 1, 64);
        if (lane == 0) excl = 1.f;

        const float w = alpha * T * excl;
        ar = fmaf(w, cr, ar);
        ag = fmaf(w, cg, ag);
        ab = fmaf(w, cb, ab);

        T *= __shfl(incl, 63, 64);

        if (__ballot(valid) == 0ull) break;
        if (T < 1e-5f) break;
    }

    #pragma unroll
    for (int off = 32; off > 0; off >>= 1) {
        ar += __shfl_down(ar, off, 64);
        ag += __shfl_down(ag, off, 64);
        ab += __shfl_down(ab, off, 64);
    }
    if (lane == 0) {
        out[wave * 3 + 0] = ar + T;
        out[wave * 3 + 1] = ag + T;
        out[wave * 3 + 2] = ab + T;
    }
}

extern "C" void kernel_launch(void* const* d_in, const int* in_sizes, int n_in,
                              void* d_out, int out_size, void* d_ws, size_t ws_size,
                              hipStream_t stream) {
    const float* rays_o  = (const float*)d_in[0];
    const float* rays_d  = (const float*)d_in[1];
    const float* density = (const float*)d_in[2];
    const float* k0      = (const float*)d_in[3];
    float* out = (float*)d_out;
    const int N = in_sizes[0] / 3;

    const int blocks = (N * 64 + 255) / 256;

    // ws layout: packed grid | order[N]  (order doubles as overrun pad for z-pair loads)
    const size_t grid_b = (size_t)G3 * 4;
    const size_t need   = grid_b + (size_t)N * 4;

    if (ws_size >= need && N == MAXRAYS) {
        unsigned int* packed = (unsigned int*)d_ws;
        unsigned int* order  = (unsigned int*)((char*)d_ws + grid_b);
        const int pack_blocks = (G3 + 4095) / 4096;   // 1000
        prep_fused<<<pack_blocks + SORT_BLOCKS, 1024, 0, stream>>>(density, k0, rays_o, rays_d,
                                                                   packed, order, N);
        dvgo_render_u8<<<blocks, 256, 0, stream>>>(rays_o, rays_d, packed, order, out, N);
    } else {
        dvgo_render_f32<<<blocks, 256, 0, stream>>>(rays_o, rays_d, density, k0, out, N);
    }
}